// Round 23
// baseline (347.922 us; speedup 1.0000x reference)
//
#include <hip/hip_runtime.h>
#include <hip/hip_bf16.h>
#include <cstdint>
#include <cstddef>

typedef __hip_bfloat16 bf16;
using f32x4  = __attribute__((ext_vector_type(4))) float;
using bf16x8 = __attribute__((ext_vector_type(8))) short;

#define DEVI __device__ __forceinline__
#define WAITVM(N) asm volatile("s_waitcnt vmcnt(" #N ")" ::: "memory")

DEVI int reg3(int u) { return (u < 49) ? 0 : ((u < 53) ? 1 : 2); }

DEVI unsigned short f2bu(float v) {
  bf16 b = __float2bfloat16(v);
  return *reinterpret_cast<unsigned short*>(&b);
}

DEVI float b2f(unsigned short u) {
  union { float f; unsigned int i; } c; c.i = ((unsigned int)u) << 16; return c.f;
}

// sigmoid-form GELU: v * sigmoid(1.702 v) — 5 VALU ops; error ~1e-3 at these activations.
DEVI float gelu_f(float v) {
  const float e = __expf(-1.702f * v);
  return v * __builtin_amdgcn_rcpf(1.0f + e);
}

DEVI void gload_lds16(const void* g, void* l) {
  __builtin_amdgcn_global_load_lds(
      (const __attribute__((address_space(1))) unsigned int*)g,
      (__attribute__((address_space(3))) unsigned int*)l, 16, 0, 0);
}

// ---------- fp32 -> bf16 weight conversion ----------
__global__ __launch_bounds__(256) void cvt_kernel(const float* __restrict__ src,
                                                  bf16* __restrict__ dst, int n)
{
  const int i = blockIdx.x * 256 + threadIdx.x;
  if (i < n) dst[i] = __float2bfloat16(src[i]);
}

// ---------- persistent-B GEMM + fused LayerNorm A-staging, K=192 ----------
// MODE 0: QKV — A rows = LN1(x fp32, gathered via shift/window +3 map); bf16 out
// MODE 2: fc1 — A rows = LN2(xb bf16, linear rows); bf16 out + GELU
template<int MODE>
__global__ __launch_bounds__(512) void plngemm_kernel(const void* __restrict__ Xv,
                                                      const float* __restrict__ gw,
                                                      const float* __restrict__ bw,
                                                      const bf16* __restrict__ Bt,
                                                      const float* __restrict__ bias,
                                                      bf16* __restrict__ outp,
                                                      int N, int grow0, int MT)
{
  __shared__ short Bp[192 * 192];       // 72 KiB
  __shared__ short La[2][64 * 192];     // 2 x 24 KiB
  const int tid   = threadIdx.x;
  const int lane  = tid & 63;
  const int w     = tid >> 6;
  const int wm    = (w >> 2) * 32;
  const int wn    = (w & 3) * 48;
  const int n0    = blockIdx.x * 192;
  const int G     = gridDim.y;
  const int g     = blockIdx.y;
  const int kq    = lane >> 4;
  const int rowid = tid >> 3;           // 0..63
  const int sub   = tid & 7;            // 8 threads per row
  const int c24   = sub * 24;

  float bv[3];
  int ncol[3];
#pragma unroll
  for (int nf = 0; nf < 3; nf++) {
    ncol[nf] = n0 + wn + nf * 16 + (lane & 15);
    bv[nf]   = bias[ncol[nf]];
  }
  float gv[24], bb[24];
#pragma unroll
  for (int i = 0; i < 6; i++) {
    const f32x4 gg = *(const f32x4*)(gw + c24 + 4 * i);
    const f32x4 bz = *(const f32x4*)(bw + c24 + 4 * i);
#pragma unroll
    for (int e = 0; e < 4; e++) { gv[4 * i + e] = gg[e]; bb[4 * i + e] = bz[e]; }
  }

#pragma unroll
  for (int i = 0; i < 9; i++) {
    const int chunk = w * 9 + i;
    const int idx = chunk * 64 + lane;
    const int row = idx / 24;
    const int seg = idx - row * 24;
    const int ksrc = (seg * 8) ^ ((row & 7) << 3);
    gload_lds16(Bt + (size_t)(n0 + row) * 192 + ksrc, Bp + chunk * 512);
  }

  f32x4 vf[6];        // MODE 0 staging (fp32)
  bf16x8 vfb[3];      // MODE 2 staging (bf16)
  auto issueA = [&](int mt) {
    if constexpr (MODE == 0) {
      const int gm  = grow0 + mt * 64 + rowid;
      const int wid = gm / 49;
      const int nn  = gm - wid * 49;
      const int b_  = wid >> 6, wim = wid & 63;
      const int wy  = wim >> 3, wx = wim & 7;
      const int ny  = nn / 7, nx = nn - (nn / 7) * 7;
      int i2 = wy * 7 + ny + 3; if (i2 >= 56) i2 -= 56;
      int j2 = wx * 7 + nx + 3; if (j2 >= 56) j2 -= 56;
      const float* src = (const float*)Xv + (size_t)(b_ * 3136 + i2 * 56 + j2) * 192 + c24;
#pragma unroll
      for (int i = 0; i < 6; i++) vf[i] = *(const f32x4*)(src + 4 * i);
    } else {
      const unsigned short* src = (const unsigned short*)Xv
                                + (size_t)(mt * 64 + rowid) * 192 + c24;
#pragma unroll
      for (int i = 0; i < 3; i++) vfb[i] = *(const bf16x8*)(src + 8 * i);
    }
  };

  auto lnwrite = [&](int buf) {
    float v[24];
    if constexpr (MODE == 0) {
#pragma unroll
      for (int i = 0; i < 6; i++)
#pragma unroll
        for (int e = 0; e < 4; e++) v[4 * i + e] = vf[i][e];
    } else {
#pragma unroll
      for (int i = 0; i < 3; i++)
#pragma unroll
        for (int e = 0; e < 8; e++) v[8 * i + e] = b2f((unsigned short)vfb[i][e]);
    }
    float s = 0.f;
#pragma unroll
    for (int i = 0; i < 24; i++) s += v[i];
    s += __shfl_xor(s, 1); s += __shfl_xor(s, 2); s += __shfl_xor(s, 4);
    const float mu = s * (1.0f / 192.0f);
    float vs = 0.f;
#pragma unroll
    for (int i = 0; i < 24; i++) { const float d = v[i] - mu; vs += d * d; }
    vs += __shfl_xor(vs, 1); vs += __shfl_xor(vs, 2); vs += __shfl_xor(vs, 4);
    const float rstd = rsqrtf(vs * (1.0f / 192.0f) + 1e-5f);
    const float a = rstd, b0 = -mu * rstd;
    const int rx = (rowid & 7) << 4;
#pragma unroll
    for (int c3 = 0; c3 < 3; c3++) {
      bf16x8 pk;
#pragma unroll
      for (int e = 0; e < 8; e++) {
        const int i = c3 * 8 + e;
        pk[e] = (short)f2bu((v[i] * a + b0) * gv[i] + bb[i]);
      }
      *(bf16x8*)((char*)&La[buf][0] + rowid * 384 + ((c24 * 2 + c3 * 16) ^ rx)) = pk;
    }
  };

  if (g < MT) { issueA(g); lnwrite(0); }
  __syncthreads();

  int buf = 0;
  for (int mt = g; mt < MT; mt += G) {
    const bool pf = (mt + G < MT);
    if (pf) issueA(mt + G);
    asm volatile("" ::: "memory");

    const char* LA = (const char*)&La[buf][0];
    f32x4 acc[2][3];
#pragma unroll
    for (int i = 0; i < 2; i++)
#pragma unroll
      for (int j = 0; j < 3; j++) acc[i][j] = (f32x4){0.f, 0.f, 0.f, 0.f};

#pragma unroll
    for (int kk = 0; kk < 6; kk++) {
      const int q = kk * 64 + (kq << 4);
      bf16x8 af[2], bg[3];
#pragma unroll
      for (int mf = 0; mf < 2; mf++) {
        const int ar = wm + mf * 16 + (lane & 15);
        af[mf] = *(const bf16x8*)(LA + ar * 384 + (q ^ ((ar & 7) << 4)));
      }
#pragma unroll
      for (int nf = 0; nf < 3; nf++) {
        const int br = wn + nf * 16 + (lane & 15);
        bg[nf] = *(const bf16x8*)((const char*)Bp + br * 384 + (q ^ ((br & 7) << 4)));
      }
#pragma unroll
      for (int mf = 0; mf < 2; mf++)
#pragma unroll
        for (int nf = 0; nf < 3; nf++)
          acc[mf][nf] = __builtin_amdgcn_mfma_f32_16x16x32_bf16(af[mf], bg[nf], acc[mf][nf], 0, 0, 0);
    }

    const int m0 = mt * 64;
#pragma unroll
    for (int mf = 0; mf < 2; mf++) {
#pragma unroll
      for (int r = 0; r < 4; r++) {
        const int m = m0 + wm + mf * 16 + ((lane >> 4) << 2) + r;
        bf16* O = outp + (size_t)m * N;
#pragma unroll
        for (int nf = 0; nf < 3; nf++) {
          float vvv = acc[mf][nf][r] + bv[nf];
          if constexpr (MODE == 2) vvv = gelu_f(vvv);
          O[ncol[nf]] = __float2bfloat16(vvv);
        }
      }
    }

    if (pf) lnwrite(buf ^ 1);
    asm volatile("s_waitcnt lgkmcnt(0)" ::: "memory");
    __builtin_amdgcn_s_barrier();
    buf ^= 1;
  }
}

// ---------- persistent-B GEMM, K=192 (proj + un-shift scatter + resid) ----------
// R23: dual-write — fp32 out (residual stream) AND bf16 xb (fc1's A input).
// vmcnt audit: per tile issue order = [3 stageA loads][24 resid loads][48 stores];
// at next-iter top WAITVM(48) retires >= the 3 oldest (stageA) -> safe.
__global__ __launch_bounds__(512) void pgemm_kernel(const bf16* __restrict__ A,
                                                    const bf16* __restrict__ Bt,
                                                    const float* __restrict__ bias,
                                                    const float* __restrict__ resid,
                                                    float* __restrict__ outv,
                                                    bf16* __restrict__ xb,
                                                    int grow0, int MT)
{
  __shared__ short Bp[192 * 192];
  __shared__ short La[2][64 * 192];
  const int tid  = threadIdx.x;
  const int lane = tid & 63;
  const int w    = tid >> 6;
  const int wm   = (w >> 2) * 32;
  const int wn   = (w & 3) * 48;
  const int n0   = blockIdx.x * 192;
  const int G    = gridDim.y;
  const int g    = blockIdx.y;
  const int kq   = lane >> 4;

  float bv[3];
  int ncol[3];
#pragma unroll
  for (int nf = 0; nf < 3; nf++) {
    ncol[nf] = n0 + wn + nf * 16 + (lane & 15);
    bv[nf]   = bias[ncol[nf]];
  }

#pragma unroll
  for (int i = 0; i < 9; i++) {
    const int chunk = w * 9 + i;
    const int idx = chunk * 64 + lane;
    const int row = idx / 24;
    const int seg = idx - row * 24;
    const int ksrc = (seg * 8) ^ ((row & 7) << 3);
    gload_lds16(Bt + (size_t)(n0 + row) * 192 + ksrc, Bp + chunk * 512);
  }

  auto stageA = [&](int buf, int mt) {
    const int m0 = mt * 64;
#pragma unroll
    for (int i = 0; i < 3; i++) {
      const int chunk = w * 3 + i;
      const int idx = chunk * 64 + lane;
      const int row = idx / 24;
      const int seg = idx - row * 24;
      const int ksrc = (seg * 8) ^ ((row & 7) << 3);
      gload_lds16(A + (size_t)(m0 + row) * 192 + ksrc, &La[buf][0] + chunk * 512);
    }
  };

  int buf = 0;
  if (g < MT) stageA(0, g);
  __syncthreads();

  for (int mt = g; mt < MT; mt += G) {
    WAITVM(48);
    __builtin_amdgcn_s_barrier();

    const char* LA = (const char*)&La[buf][0];
    f32x4 acc[2][3];
#pragma unroll
    for (int i = 0; i < 2; i++)
#pragma unroll
      for (int j = 0; j < 3; j++) acc[i][j] = (f32x4){0.f, 0.f, 0.f, 0.f};

#pragma unroll
    for (int kk = 0; kk < 6; kk++) {
      const int q = kk * 64 + (kq << 4);
      bf16x8 af[2], bg[3];
#pragma unroll
      for (int mf = 0; mf < 2; mf++) {
        const int ar = wm + mf * 16 + (lane & 15);
        af[mf] = *(const bf16x8*)(LA + ar * 384 + (q ^ ((ar & 7) << 4)));
      }
#pragma unroll
      for (int nf = 0; nf < 3; nf++) {
        const int br = wn + nf * 16 + (lane & 15);
        bg[nf] = *(const bf16x8*)((const char*)Bp + br * 384 + (q ^ ((br & 7) << 4)));
      }
#pragma unroll
      for (int mf = 0; mf < 2; mf++)
#pragma unroll
        for (int nf = 0; nf < 3; nf++)
          acc[mf][nf] = __builtin_amdgcn_mfma_f32_16x16x32_bf16(af[mf], bg[nf], acc[mf][nf], 0, 0, 0);
    }

    if (mt + G < MT) stageA(buf ^ 1, mt + G);

    const int m0 = mt * 64;
#pragma unroll
    for (int mf = 0; mf < 2; mf++) {
#pragma unroll
      for (int r = 0; r < 4; r++) {
        const int m = m0 + wm + mf * 16 + ((lane >> 4) << 2) + r;
        const int gm  = grow0 + m;
        const int wid = gm / 49;
        const int nn  = gm - wid * 49;
        const int b_  = wid >> 6, wim = wid & 63;
        const int wy  = wim >> 3, wx = wim & 7;
        const int ny  = nn / 7, nx = nn - (nn / 7) * 7;
        int i = wy * 7 + ny + 3; if (i >= 56) i -= 56;
        int j = wx * 7 + nx + 3; if (j >= 56) j -= 56;
        const size_t t = (size_t)(b_ * 3136 + i * 56 + j) * 192;
#pragma unroll
        for (int nf = 0; nf < 3; nf++) {
          const float val = acc[mf][nf][r] + bv[nf] + resid[t + ncol[nf]];
          outv[t + ncol[nf]] = val;
          xb[t + ncol[nf]]   = __float2bfloat16(val);
        }
      }
    }
    buf ^= 1;
  }
}

// ---------- streamed GEMM (fc2: K=768, fp32 +=), counted-vmcnt 2-phase ----------
__global__ __launch_bounds__(512, 4) void gemm_kernel(const bf16* __restrict__ A,
                                                      const bf16* __restrict__ Bt,
                                                      const float* __restrict__ bias,
                                                      void* __restrict__ outv,
                                                      int N, int K)
{
  __shared__ short lds[2][128 * 64 + 192 * 64];
  const int tid  = threadIdx.x;
  const int lane = tid & 63;
  const int w    = tid >> 6;
  const int wm   = (w >> 2) * 64;
  const int wn   = (w & 3) * 48;
  const int m0   = blockIdx.y * 128;
  const int n0   = blockIdx.x * 192;
  const int lrow = lane >> 3;
  const int lseg = lane & 7;
  const int ksw  = (lseg * 8) ^ (lrow << 3);

  f32x4 acc[4][3];
#pragma unroll
  for (int i = 0; i < 4; i++)
#pragma unroll
    for (int j = 0; j < 3; j++) acc[i][j] = (f32x4){0.f, 0.f, 0.f, 0.f};

  const int nk = K >> 6;

  auto issue = [&](int buf, int kt) {
    const int k0 = kt << 6;
    short* LA = &lds[buf][0];
    short* LB = &lds[buf][128 * 64];
#pragma unroll
    for (int i = 0; i < 2; i++) {
      const int chunk = w * 2 + i;
      gload_lds16(A + (size_t)(m0 + chunk * 8 + lrow) * K + (k0 + ksw), LA + chunk * 512);
    }
#pragma unroll
    for (int i = 0; i < 3; i++) {
      const int chunk = w * 3 + i;
      gload_lds16(Bt + (size_t)(n0 + chunk * 8 + lrow) * K + (k0 + ksw), LB + chunk * 512);
    }
  };

  issue(0, 0);
  __syncthreads();
  int buf = 0;

  for (int kt = 0; kt < nk; kt++) {
    if (kt + 1 < nk) {
      issue(buf ^ 1, kt + 1);
      WAITVM(5);
    } else {
      WAITVM(0);
    }
    __builtin_amdgcn_s_barrier();
    const char* LA = (const char*)&lds[buf][0];
    const char* LB = (const char*)&lds[buf][128 * 64];
#pragma unroll
    for (int kk = 0; kk < 2; kk++) {
      bf16x8 af[4], bg[3];
#pragma unroll
      for (int mf = 0; mf < 4; mf++) {
        const int row = wm + mf * 16 + (lane & 15);
        const int kb  = (kk * 64 + ((lane >> 4) << 4)) ^ ((row & 7) << 4);
        af[mf] = *(const bf16x8*)(LA + row * 128 + kb);
      }
#pragma unroll
      for (int nf = 0; nf < 3; nf++) {
        const int row = wn + nf * 16 + (lane & 15);
        const int kb  = (kk * 64 + ((lane >> 4) << 4)) ^ ((row & 7) << 4);
        bg[nf] = *(const bf16x8*)(LB + row * 128 + kb);
      }
#pragma unroll
      for (int mf = 0; mf < 4; mf++)
#pragma unroll
        for (int nf = 0; nf < 3; nf++)
          acc[mf][nf] = __builtin_amdgcn_mfma_f32_16x16x32_bf16(af[mf], bg[nf], acc[mf][nf], 0, 0, 0);
    }
    __builtin_amdgcn_s_barrier();
    buf ^= 1;
  }

  float bv[3];
  int ncol[3];
#pragma unroll
  for (int nf = 0; nf < 3; nf++) {
    ncol[nf] = n0 + wn + nf * 16 + (lane & 15);
    bv[nf]   = bias[ncol[nf]];
  }
#pragma unroll
  for (int mf = 0; mf < 4; mf++) {
#pragma unroll
    for (int r = 0; r < 4; r++) {
      const int m = m0 + wm + mf * 16 + ((lane >> 4) << 2) + r;
      float* O = (float*)outv + (size_t)m * N;
#pragma unroll
      for (int nf = 0; nf < 3; nf++)
        O[ncol[nf]] = acc[mf][nf][r] + bv[nf] + O[ncol[nf]];
    }
  }
}

// ---------- MFMA windowed attention (R7-verified; rcp normalize; T5 setprio) ----------
__global__ __launch_bounds__(64) void attn_kernel(const bf16* __restrict__ qkv,
                                                  const float* __restrict__ rpb,
                                                  bf16* __restrict__ aout)
{
  __shared__ unsigned short Vt[32 * 64];
  __shared__ unsigned short Pl[64 * 64];
  __shared__ float Bl[169];
  const int lane = threadIdx.x;
  const int wid  = blockIdx.x;
  const int h    = blockIdx.y;
  const unsigned short* qkvu = (const unsigned short*)qkv;
  const size_t base = (size_t)wid * 49 * 576 + h * 32;

#pragma unroll
  for (int i = 0; i < 3; i++) {
    const int idx = lane + 64 * i;
    if (idx < 169) Bl[idx] = rpb[idx * 6 + h];
  }
#pragma unroll
  for (int i = 0; i < 8; i++)
    ((unsigned long long*)Vt)[lane + 64 * i] = 0ull;

#pragma unroll
  for (int it = 0; it < 7; it++) {
    const int idx = lane + 64 * it;
    if (idx < 392) {
      const int n  = idx >> 3;
      const int d0 = (idx & 7) * 4;
      ushort4 v = *(const ushort4*)(qkvu + base + (size_t)n * 576 + 384 + d0);
      Vt[(d0 + 0) * 64 + (n ^ (((d0 + 0) & 7) << 3))] = v.x;
      Vt[(d0 + 1) * 64 + (n ^ (((d0 + 1) & 7) << 3))] = v.y;
      Vt[(d0 + 2) * 64 + (n ^ (((d0 + 2) & 7) << 3))] = v.z;
      Vt[(d0 + 3) * 64 + (n ^ (((d0 + 3) & 7) << 3))] = v.w;
    }
  }

  bf16x8 qf[4], kf[4];
#pragma unroll
  for (int t = 0; t < 4; t++) {
    int rq = (lane & 15) + t * 16; if (rq > 48) rq = 48;
    qf[t] = *(const bf16x8*)(qkvu + base + (size_t)rq * 576 + ((lane >> 4) * 8));
    kf[t] = *(const bf16x8*)(qkvu + base + (size_t)rq * 576 + 192 + ((lane >> 4) * 8));
  }

  f32x4 s[4][4];
  __builtin_amdgcn_s_setprio(1);
#pragma unroll
  for (int mt = 0; mt < 4; mt++)
#pragma unroll
    for (int nt = 0; nt < 4; nt++)
      s[mt][nt] = __builtin_amdgcn_mfma_f32_16x16x32_bf16(qf[mt], kf[nt],
                    (f32x4){0.f, 0.f, 0.f, 0.f}, 0, 0, 0);
  __builtin_amdgcn_s_setprio(0);

  const int wim = wid & 63;
  const int wy = wim >> 3, wx = wim & 7;
  int labn[4], ch[4], cw[4];
  bool cval[4];
#pragma unroll
  for (int nt = 0; nt < 4; nt++) {
    const int C = (lane & 15) + nt * 16;
    cval[nt] = (C < 49);
    const int cc = cval[nt] ? C : 48;
    ch[nt] = cc / 7; cw[nt] = cc - ch[nt] * 7;
    labn[nt] = reg3(wy * 7 + ch[nt]) * 3 + reg3(wx * 7 + cw[nt]);
  }

#pragma unroll
  for (int mt = 0; mt < 4; mt++) {
    f32x4 rm, sm, inv;
#pragma unroll
    for (int r = 0; r < 4; r++) {
      int R = mt * 16 + ((lane >> 4) << 2) + r; if (R > 48) R = 48;
      const int mh = R / 7, mw = R - (R / 7) * 7;
      const int labm = reg3(wy * 7 + mh) * 3 + reg3(wx * 7 + mw);
#pragma unroll
      for (int nt = 0; nt < 4; nt++) {
        float sv = s[mt][nt][r] * 0.1767766953f
                 + Bl[(mh - ch[nt] + 6) * 13 + (mw - cw[nt] + 6)];
        if (labn[nt] != labm) sv -= 100.f;
        if (!cval[nt]) sv = -3e38f;
        s[mt][nt][r] = sv;
      }
      rm[r] = fmaxf(fmaxf(s[mt][0][r], s[mt][1][r]), fmaxf(s[mt][2][r], s[mt][3][r]));
    }
#pragma unroll
    for (int mk = 1; mk < 16; mk <<= 1)
#pragma unroll
      for (int r = 0; r < 4; r++) rm[r] = fmaxf(rm[r], __shfl_xor(rm[r], mk));
#pragma unroll
    for (int r = 0; r < 4; r++) {
      float acc = 0.f;
#pragma unroll
      for (int nt = 0; nt < 4; nt++) {
        const float p = __expf(s[mt][nt][r] - rm[r]);
        s[mt][nt][r] = p;
        acc += p;
      }
      sm[r] = acc;
    }
#pragma unroll
    for (int mk = 1; mk < 16; mk <<= 1)
#pragma unroll
      for (int r = 0; r < 4; r++) sm[r] += __shfl_xor(sm[r], mk);
#pragma unroll
    for (int r = 0; r < 4; r++) inv[r] = __builtin_amdgcn_rcpf(sm[r]);
#pragma unroll
    for (int nt = 0; nt < 4; nt++)
#pragma unroll
      for (int r = 0; r < 4; r++) {
        const int R = mt * 16 + ((lane >> 4) << 2) + r;
        const int C = (lane & 15) + nt * 16;
        Pl[R * 64 + (C ^ ((R & 7) << 3))] = f2bu(s[mt][nt][r] * inv[r]);
      }
  }

  f32x4 o[4][2];
#pragma unroll
  for (int mt = 0; mt < 4; mt++)
#pragma unroll
    for (int n2 = 0; n2 < 2; n2++) o[mt][n2] = (f32x4){0.f, 0.f, 0.f, 0.f};
  __builtin_amdgcn_s_setprio(1);
#pragma unroll
  for (int kk = 0; kk < 2; kk++) {
    const int kb = kk * 64 + ((lane >> 4) << 4);
    bf16x8 vb[2];
#pragma unroll
    for (int n2 = 0; n2 < 2; n2++) {
      const int d = (lane & 15) + n2 * 16;
      vb[n2] = *(const bf16x8*)((const char*)Vt + d * 128 + (kb ^ ((d & 7) << 4)));
    }
#pragma unroll
    for (int mt = 0; mt < 4; mt++) {
      const int R = (lane & 15) + mt * 16;
      const bf16x8 pa = *(const bf16x8*)((const char*)Pl + R * 128 + (kb ^ ((R & 7) << 4)));
#pragma unroll
      for (int n2 = 0; n2 < 2; n2++)
        o[mt][n2] = __builtin_amdgcn_mfma_f32_16x16x32_bf16(pa, vb[n2], o[mt][n2], 0, 0, 0);
    }
  }
  __builtin_amdgcn_s_setprio(0);

#pragma unroll
  for (int mt = 0; mt < 4; mt++)
#pragma unroll
    for (int r = 0; r < 4; r++) {
      const int R = mt * 16 + ((lane >> 4) << 2) + r;
      if (R < 49) {
        bf16* orow = aout + (size_t)(wid * 49 + R) * 192 + h * 32;
#pragma unroll
        for (int n2 = 0; n2 < 2; n2++)
          orow[n2 * 16 + (lane & 15)] = __float2bfloat16(o[mt][n2][r]);
      }
    }
}

extern "C" void kernel_launch(void* const* d_in, const int* in_sizes, int n_in,
                              void* d_out, int out_size, void* d_ws, size_t ws_size,
                              hipStream_t stream)
{
  (void)in_sizes; (void)n_in; (void)out_size;
  const float* x     = (const float*)d_in[0];
  const float* ln1g  = (const float*)d_in[1];
  const float* ln1b  = (const float*)d_in[2];
  const float* qkvw  = (const float*)d_in[3];
  const float* qkvb  = (const float*)d_in[4];
  const float* projw = (const float*)d_in[5];
  const float* projb = (const float*)d_in[6];
  const float* rpb   = (const float*)d_in[7];
  const float* ln2g  = (const float*)d_in[8];
  const float* ln2b  = (const float*)d_in[9];
  const float* fc1w  = (const float*)d_in[10];
  const float* fc1b  = (const float*)d_in[11];
  const float* fc2w  = (const float*)d_in[12];
  const float* fc2b  = (const float*)d_in[13];
  float* out = (float*)d_out;
  char* ws   = (char*)d_ws;

  // ---- bf16 weight copies (884736 B) + xb buffer (38535168 B) ----
  bf16* wqkv = (bf16*)(ws);              // 110592 el
  bf16* wproj = (bf16*)(ws + 221184);    //  36864 el
  bf16* wfc1 = (bf16*)(ws + 294912);     // 147456 el
  bf16* wfc2 = (bf16*)(ws + 589824);     // 147456 el
  bf16* xb   = (bf16*)(ws + 884736);     // bf16 copy of x2 (fc1 A input)
  cvt_kernel<<<dim3(432), dim3(256), 0, stream>>>(qkvw, wqkv, 110592);
  cvt_kernel<<<dim3(144), dim3(256), 0, stream>>>(projw, wproj, 36864);
  cvt_kernel<<<dim3(576), dim3(256), 0, stream>>>(fc1w, wfc1, 147456);
  cvt_kernel<<<dim3(576), dim3(256), 0, stream>>>(fc2w, wfc2, 147456);

  const size_t head = 884736ull + 38535168ull;
  char* cws = ws + head;
  const size_t avail = (ws_size > head) ? ws_size - head : 0;

  // ---- attention pipeline, chunked over batch (permutes are batch-local) ----
  int Bc = 32;
  while (Bc > 2 && (size_t)Bc * 4816896ull > avail) Bc >>= 1;
  const int nb = 32 / Bc;
  bf16* qkv_c  = (bf16*)cws;
  bf16* hwin_c = (bf16*)(cws + (size_t)Bc * 3612672ull);   // attnout

  for (int c = 0; c < nb; c++) {
    const int R0 = c * Bc * 3136;
    const int Mc = Bc * 3136;
    const int MT = Mc / 64;
    const int Gq = (MT < 85) ? MT : 85;
    const int Gp = (MT < 256) ? MT : 256;
    plngemm_kernel<0><<<dim3(3, Gq), dim3(512), 0, stream>>>(x, ln1g, ln1b, wqkv, qkvb,
                                                             qkv_c, 576, R0, MT);
    attn_kernel<<<dim3(Bc * 64, 6), dim3(64), 0, stream>>>(qkv_c, rpb, hwin_c);
    pgemm_kernel<<<dim3(1, Gp), dim3(512), 0, stream>>>(hwin_c, wproj, projb, x, out, xb, R0, MT);
  }

  // ---- MLP: fc1 (LN2 fused, bf16 A from xb), then fc2 ----
  int Rc = 100352;
  while (Rc > 6272 && (size_t)Rc * 1536ull > avail) Rc >>= 1;
  bf16* a1_c = (bf16*)cws;

  for (int r0 = 0; r0 < 100352; r0 += Rc) {
    const int MT1 = Rc / 64;
    const int G1  = (MT1 < 64) ? MT1 : 64;
    plngemm_kernel<2><<<dim3(4, G1), dim3(512), 0, stream>>>(xb + (size_t)r0 * 192,
                                                             ln2g, ln2b, wfc1, fc1b,
                                                             a1_c, 768, 0, MT1);
    gemm_kernel<<<dim3(1, Rc / 128), dim3(512), 0, stream>>>(a1_c, wfc2, fc2b,
                                                             out + (size_t)r0 * 192, 192, 768);
  }
}

// Round 24
// 326.299 us; speedup vs baseline: 1.0663x; 1.0663x over previous
//
#include <hip/hip_runtime.h>
#include <hip/hip_bf16.h>
#include <cstdint>
#include <cstddef>

typedef __hip_bfloat16 bf16;
using f32x4  = __attribute__((ext_vector_type(4))) float;
using bf16x8 = __attribute__((ext_vector_type(8))) short;

#define DEVI __device__ __forceinline__
#define WAITVM(N) asm volatile("s_waitcnt vmcnt(" #N ")" ::: "memory")

DEVI int reg3(int u) { return (u < 49) ? 0 : ((u < 53) ? 1 : 2); }

DEVI unsigned short f2bu(float v) {
  bf16 b = __float2bfloat16(v);
  return *reinterpret_cast<unsigned short*>(&b);
}

// sigmoid-form GELU: v * sigmoid(1.702 v) — 5 VALU ops; error ~1e-3 at these activations.
DEVI float gelu_f(float v) {
  const float e = __expf(-1.702f * v);
  return v * __builtin_amdgcn_rcpf(1.0f + e);
}

DEVI void gload_lds16(const void* g, void* l) {
  __builtin_amdgcn_global_load_lds(
      (const __attribute__((address_space(1))) unsigned int*)g,
      (__attribute__((address_space(3))) unsigned int*)l, 16, 0, 0);
}

// ---------- fp32 -> bf16 weight conversion ----------
__global__ __launch_bounds__(256) void cvt_kernel(const float* __restrict__ src,
                                                  bf16* __restrict__ dst, int n)
{
  const int i = blockIdx.x * 256 + threadIdx.x;
  if (i < n) dst[i] = __float2bfloat16(src[i]);
}

// ---------- persistent-B GEMM + fused LayerNorm A-staging, K=192 ----------
// MODE 0: QKV — A rows = LN1(x[gathered via shift/window +3 map]); bf16 out
// MODE 2: fc1 — A rows = LN2(X linear rows); bf16 out + GELU
template<int MODE>
__global__ __launch_bounds__(512) void plngemm_kernel(const float* __restrict__ X,
                                                      const float* __restrict__ gw,
                                                      const float* __restrict__ bw,
                                                      const bf16* __restrict__ Bt,
                                                      const float* __restrict__ bias,
                                                      bf16* __restrict__ outp,
                                                      int N, int grow0, int MT)
{
  __shared__ short Bp[192 * 192];       // 72 KiB
  __shared__ short La[2][64 * 192];     // 2 x 24 KiB
  const int tid   = threadIdx.x;
  const int lane  = tid & 63;
  const int w     = tid >> 6;
  const int wm    = (w >> 2) * 32;
  const int wn    = (w & 3) * 48;
  const int n0    = blockIdx.x * 192;
  const int G     = gridDim.y;
  const int g     = blockIdx.y;
  const int kq    = lane >> 4;
  const int rowid = tid >> 3;           // 0..63
  const int sub   = tid & 7;            // 8 threads per row
  const int c24   = sub * 24;

  float bv[3];
  int ncol[3];
#pragma unroll
  for (int nf = 0; nf < 3; nf++) {
    ncol[nf] = n0 + wn + nf * 16 + (lane & 15);
    bv[nf]   = bias[ncol[nf]];
  }
  float gv[24], bb[24];
#pragma unroll
  for (int i = 0; i < 6; i++) {
    const f32x4 gg = *(const f32x4*)(gw + c24 + 4 * i);
    const f32x4 bz = *(const f32x4*)(bw + c24 + 4 * i);
#pragma unroll
    for (int e = 0; e < 4; e++) { gv[4 * i + e] = gg[e]; bb[4 * i + e] = bz[e]; }
  }

#pragma unroll
  for (int i = 0; i < 9; i++) {
    const int chunk = w * 9 + i;
    const int idx = chunk * 64 + lane;
    const int row = idx / 24;
    const int seg = idx - row * 24;
    const int ksrc = (seg * 8) ^ ((row & 7) << 3);
    gload_lds16(Bt + (size_t)(n0 + row) * 192 + ksrc, Bp + chunk * 512);
  }

  f32x4 vf[6];
  auto issueA = [&](int mt) {
    const float* src;
    if constexpr (MODE == 0) {
      const int gm  = grow0 + mt * 64 + rowid;
      const int wid = gm / 49;
      const int nn  = gm - wid * 49;
      const int b_  = wid >> 6, wim = wid & 63;
      const int wy  = wim >> 3, wx = wim & 7;
      const int ny  = nn / 7, nx = nn - (nn / 7) * 7;
      int i2 = wy * 7 + ny + 3; if (i2 >= 56) i2 -= 56;
      int j2 = wx * 7 + nx + 3; if (j2 >= 56) j2 -= 56;
      src = X + (size_t)(b_ * 3136 + i2 * 56 + j2) * 192 + c24;
    } else {
      src = X + (size_t)(mt * 64 + rowid) * 192 + c24;
    }
#pragma unroll
    for (int i = 0; i < 6; i++) vf[i] = *(const f32x4*)(src + 4 * i);
  };

  auto lnwrite = [&](int buf) {
    float v[24];
#pragma unroll
    for (int i = 0; i < 6; i++)
#pragma unroll
      for (int e = 0; e < 4; e++) v[4 * i + e] = vf[i][e];
    float s = 0.f;
#pragma unroll
    for (int i = 0; i < 24; i++) s += v[i];
    s += __shfl_xor(s, 1); s += __shfl_xor(s, 2); s += __shfl_xor(s, 4);
    const float mu = s * (1.0f / 192.0f);
    float vs = 0.f;
#pragma unroll
    for (int i = 0; i < 24; i++) { const float d = v[i] - mu; vs += d * d; }
    vs += __shfl_xor(vs, 1); vs += __shfl_xor(vs, 2); vs += __shfl_xor(vs, 4);
    const float rstd = rsqrtf(vs * (1.0f / 192.0f) + 1e-5f);
    const float a = rstd, b0 = -mu * rstd;
    const int rx = (rowid & 7) << 4;
#pragma unroll
    for (int c3 = 0; c3 < 3; c3++) {
      bf16x8 pk;
#pragma unroll
      for (int e = 0; e < 8; e++) {
        const int i = c3 * 8 + e;
        pk[e] = (short)f2bu((v[i] * a + b0) * gv[i] + bb[i]);
      }
      *(bf16x8*)((char*)&La[buf][0] + rowid * 384 + ((c24 * 2 + c3 * 16) ^ rx)) = pk;
    }
  };

  if (g < MT) { issueA(g); lnwrite(0); }
  __syncthreads();

  int buf = 0;
  for (int mt = g; mt < MT; mt += G) {
    const bool pf = (mt + G < MT);
    if (pf) issueA(mt + G);
    asm volatile("" ::: "memory");

    const char* LA = (const char*)&La[buf][0];
    f32x4 acc[2][3];
#pragma unroll
    for (int i = 0; i < 2; i++)
#pragma unroll
      for (int j = 0; j < 3; j++) acc[i][j] = (f32x4){0.f, 0.f, 0.f, 0.f};

#pragma unroll
    for (int kk = 0; kk < 6; kk++) {
      const int q = kk * 64 + (kq << 4);
      bf16x8 af[2], bg[3];
#pragma unroll
      for (int mf = 0; mf < 2; mf++) {
        const int ar = wm + mf * 16 + (lane & 15);
        af[mf] = *(const bf16x8*)(LA + ar * 384 + (q ^ ((ar & 7) << 4)));
      }
#pragma unroll
      for (int nf = 0; nf < 3; nf++) {
        const int br = wn + nf * 16 + (lane & 15);
        bg[nf] = *(const bf16x8*)((const char*)Bp + br * 384 + (q ^ ((br & 7) << 4)));
      }
#pragma unroll
      for (int mf = 0; mf < 2; mf++)
#pragma unroll
        for (int nf = 0; nf < 3; nf++)
          acc[mf][nf] = __builtin_amdgcn_mfma_f32_16x16x32_bf16(af[mf], bg[nf], acc[mf][nf], 0, 0, 0);
    }

    const int m0 = mt * 64;
#pragma unroll
    for (int mf = 0; mf < 2; mf++) {
#pragma unroll
      for (int r = 0; r < 4; r++) {
        const int m = m0 + wm + mf * 16 + ((lane >> 4) << 2) + r;
        bf16* O = outp + (size_t)m * N;
#pragma unroll
        for (int nf = 0; nf < 3; nf++) {
          float vvv = acc[mf][nf][r] + bv[nf];
          if constexpr (MODE == 2) vvv = gelu_f(vvv);
          O[ncol[nf]] = __float2bfloat16(vvv);
        }
      }
    }

    if (pf) lnwrite(buf ^ 1);
    asm volatile("s_waitcnt lgkmcnt(0)" ::: "memory");
    __builtin_amdgcn_s_barrier();
    buf ^= 1;
  }
}

// ---------- persistent-B GEMM, K=192 (proj + un-shift scatter + resid) ----------
__global__ __launch_bounds__(512) void pgemm_kernel(const bf16* __restrict__ A,
                                                    const bf16* __restrict__ Bt,
                                                    const float* __restrict__ bias,
                                                    const float* __restrict__ resid,
                                                    float* __restrict__ outv,
                                                    int grow0, int MT)
{
  __shared__ short Bp[192 * 192];
  __shared__ short La[2][64 * 192];
  const int tid  = threadIdx.x;
  const int lane = tid & 63;
  const int w    = tid >> 6;
  const int wm   = (w >> 2) * 32;
  const int wn   = (w & 3) * 48;
  const int n0   = blockIdx.x * 192;
  const int G    = gridDim.y;
  const int g    = blockIdx.y;
  const int kq   = lane >> 4;

  float bv[3];
  int ncol[3];
#pragma unroll
  for (int nf = 0; nf < 3; nf++) {
    ncol[nf] = n0 + wn + nf * 16 + (lane & 15);
    bv[nf]   = bias[ncol[nf]];
  }

#pragma unroll
  for (int i = 0; i < 9; i++) {
    const int chunk = w * 9 + i;
    const int idx = chunk * 64 + lane;
    const int row = idx / 24;
    const int seg = idx - row * 24;
    const int ksrc = (seg * 8) ^ ((row & 7) << 3);
    gload_lds16(Bt + (size_t)(n0 + row) * 192 + ksrc, Bp + chunk * 512);
  }

  auto stageA = [&](int buf, int mt) {
    const int m0 = mt * 64;
#pragma unroll
    for (int i = 0; i < 3; i++) {
      const int chunk = w * 3 + i;
      const int idx = chunk * 64 + lane;
      const int row = idx / 24;
      const int seg = idx - row * 24;
      const int ksrc = (seg * 8) ^ ((row & 7) << 3);
      gload_lds16(A + (size_t)(m0 + row) * 192 + ksrc, &La[buf][0] + chunk * 512);
    }
  };

  int buf = 0;
  if (g < MT) stageA(0, g);
  __syncthreads();

  for (int mt = g; mt < MT; mt += G) {
    WAITVM(48);
    __builtin_amdgcn_s_barrier();

    const char* LA = (const char*)&La[buf][0];
    f32x4 acc[2][3];
#pragma unroll
    for (int i = 0; i < 2; i++)
#pragma unroll
      for (int j = 0; j < 3; j++) acc[i][j] = (f32x4){0.f, 0.f, 0.f, 0.f};

#pragma unroll
    for (int kk = 0; kk < 6; kk++) {
      const int q = kk * 64 + (kq << 4);
      bf16x8 af[2], bg[3];
#pragma unroll
      for (int mf = 0; mf < 2; mf++) {
        const int ar = wm + mf * 16 + (lane & 15);
        af[mf] = *(const bf16x8*)(LA + ar * 384 + (q ^ ((ar & 7) << 4)));
      }
#pragma unroll
      for (int nf = 0; nf < 3; nf++) {
        const int br = wn + nf * 16 + (lane & 15);
        bg[nf] = *(const bf16x8*)((const char*)Bp + br * 384 + (q ^ ((br & 7) << 4)));
      }
#pragma unroll
      for (int mf = 0; mf < 2; mf++)
#pragma unroll
        for (int nf = 0; nf < 3; nf++)
          acc[mf][nf] = __builtin_amdgcn_mfma_f32_16x16x32_bf16(af[mf], bg[nf], acc[mf][nf], 0, 0, 0);
    }

    if (mt + G < MT) stageA(buf ^ 1, mt + G);

    const int m0 = mt * 64;
#pragma unroll
    for (int mf = 0; mf < 2; mf++) {
#pragma unroll
      for (int r = 0; r < 4; r++) {
        const int m = m0 + wm + mf * 16 + ((lane >> 4) << 2) + r;
        const int gm  = grow0 + m;
        const int wid = gm / 49;
        const int nn  = gm - wid * 49;
        const int b_  = wid >> 6, wim = wid & 63;
        const int wy  = wim >> 3, wx = wim & 7;
        const int ny  = nn / 7, nx = nn - (nn / 7) * 7;
        int i = wy * 7 + ny + 3; if (i >= 56) i -= 56;
        int j = wx * 7 + nx + 3; if (j >= 56) j -= 56;
        const size_t t = (size_t)(b_ * 3136 + i * 56 + j) * 192;
#pragma unroll
        for (int nf = 0; nf < 3; nf++)
          outv[t + ncol[nf]] = acc[mf][nf][r] + bv[nf] + resid[t + ncol[nf]];
      }
    }
    buf ^= 1;
  }
}

// ---------- streamed GEMM (fc2: K=768, fp32 +=), counted-vmcnt 2-phase ----------
__global__ __launch_bounds__(512, 4) void gemm_kernel(const bf16* __restrict__ A,
                                                      const bf16* __restrict__ Bt,
                                                      const float* __restrict__ bias,
                                                      void* __restrict__ outv,
                                                      int N, int K)
{
  __shared__ short lds[2][128 * 64 + 192 * 64];
  const int tid  = threadIdx.x;
  const int lane = tid & 63;
  const int w    = tid >> 6;
  const int wm   = (w >> 2) * 64;
  const int wn   = (w & 3) * 48;
  const int m0   = blockIdx.y * 128;
  const int n0   = blockIdx.x * 192;
  const int lrow = lane >> 3;
  const int lseg = lane & 7;
  const int ksw  = (lseg * 8) ^ (lrow << 3);

  f32x4 acc[4][3];
#pragma unroll
  for (int i = 0; i < 4; i++)
#pragma unroll
    for (int j = 0; j < 3; j++) acc[i][j] = (f32x4){0.f, 0.f, 0.f, 0.f};

  const int nk = K >> 6;

  auto issue = [&](int buf, int kt) {
    const int k0 = kt << 6;
    short* LA = &lds[buf][0];
    short* LB = &lds[buf][128 * 64];
#pragma unroll
    for (int i = 0; i < 2; i++) {
      const int chunk = w * 2 + i;
      gload_lds16(A + (size_t)(m0 + chunk * 8 + lrow) * K + (k0 + ksw), LA + chunk * 512);
    }
#pragma unroll
    for (int i = 0; i < 3; i++) {
      const int chunk = w * 3 + i;
      gload_lds16(Bt + (size_t)(n0 + chunk * 8 + lrow) * K + (k0 + ksw), LB + chunk * 512);
    }
  };

  issue(0, 0);
  __syncthreads();
  int buf = 0;

  for (int kt = 0; kt < nk; kt++) {
    if (kt + 1 < nk) {
      issue(buf ^ 1, kt + 1);
      WAITVM(5);
    } else {
      WAITVM(0);
    }
    __builtin_amdgcn_s_barrier();
    const char* LA = (const char*)&lds[buf][0];
    const char* LB = (const char*)&lds[buf][128 * 64];
#pragma unroll
    for (int kk = 0; kk < 2; kk++) {
      bf16x8 af[4], bg[3];
#pragma unroll
      for (int mf = 0; mf < 4; mf++) {
        const int row = wm + mf * 16 + (lane & 15);
        const int kb  = (kk * 64 + ((lane >> 4) << 4)) ^ ((row & 7) << 4);
        af[mf] = *(const bf16x8*)(LA + row * 128 + kb);
      }
#pragma unroll
      for (int nf = 0; nf < 3; nf++) {
        const int row = wn + nf * 16 + (lane & 15);
        const int kb  = (kk * 64 + ((lane >> 4) << 4)) ^ ((row & 7) << 4);
        bg[nf] = *(const bf16x8*)(LB + row * 128 + kb);
      }
#pragma unroll
      for (int mf = 0; mf < 4; mf++)
#pragma unroll
        for (int nf = 0; nf < 3; nf++)
          acc[mf][nf] = __builtin_amdgcn_mfma_f32_16x16x32_bf16(af[mf], bg[nf], acc[mf][nf], 0, 0, 0);
    }
    __builtin_amdgcn_s_barrier();
    buf ^= 1;
  }

  float bv[3];
  int ncol[3];
#pragma unroll
  for (int nf = 0; nf < 3; nf++) {
    ncol[nf] = n0 + wn + nf * 16 + (lane & 15);
    bv[nf]   = bias[ncol[nf]];
  }
#pragma unroll
  for (int mf = 0; mf < 4; mf++) {
#pragma unroll
    for (int r = 0; r < 4; r++) {
      const int m = m0 + wm + mf * 16 + ((lane >> 4) << 2) + r;
      float* O = (float*)outv + (size_t)m * N;
#pragma unroll
      for (int nf = 0; nf < 3; nf++)
        O[ncol[nf]] = acc[mf][nf][r] + bv[nf] + O[ncol[nf]];
    }
  }
}

// ---------- MFMA windowed attention (R7-verified; rcp normalize; T5 setprio) ----------
__global__ __launch_bounds__(64) void attn_kernel(const bf16* __restrict__ qkv,
                                                  const float* __restrict__ rpb,
                                                  bf16* __restrict__ aout)
{
  __shared__ unsigned short Vt[32 * 64];
  __shared__ unsigned short Pl[64 * 64];
  __shared__ float Bl[169];
  const int lane = threadIdx.x;
  const int wid  = blockIdx.x;
  const int h    = blockIdx.y;
  const unsigned short* qkvu = (const unsigned short*)qkv;
  const size_t base = (size_t)wid * 49 * 576 + h * 32;

#pragma unroll
  for (int i = 0; i < 3; i++) {
    const int idx = lane + 64 * i;
    if (idx < 169) Bl[idx] = rpb[idx * 6 + h];
  }
#pragma unroll
  for (int i = 0; i < 8; i++)
    ((unsigned long long*)Vt)[lane + 64 * i] = 0ull;

#pragma unroll
  for (int it = 0; it < 7; it++) {
    const int idx = lane + 64 * it;
    if (idx < 392) {
      const int n  = idx >> 3;
      const int d0 = (idx & 7) * 4;
      ushort4 v = *(const ushort4*)(qkvu + base + (size_t)n * 576 + 384 + d0);
      Vt[(d0 + 0) * 64 + (n ^ (((d0 + 0) & 7) << 3))] = v.x;
      Vt[(d0 + 1) * 64 + (n ^ (((d0 + 1) & 7) << 3))] = v.y;
      Vt[(d0 + 2) * 64 + (n ^ (((d0 + 2) & 7) << 3))] = v.z;
      Vt[(d0 + 3) * 64 + (n ^ (((d0 + 3) & 7) << 3))] = v.w;
    }
  }

  bf16x8 qf[4], kf[4];
#pragma unroll
  for (int t = 0; t < 4; t++) {
    int rq = (lane & 15) + t * 16; if (rq > 48) rq = 48;
    qf[t] = *(const bf16x8*)(qkvu + base + (size_t)rq * 576 + ((lane >> 4) * 8));
    kf[t] = *(const bf16x8*)(qkvu + base + (size_t)rq * 576 + 192 + ((lane >> 4) * 8));
  }

  f32x4 s[4][4];
  __builtin_amdgcn_s_setprio(1);
#pragma unroll
  for (int mt = 0; mt < 4; mt++)
#pragma unroll
    for (int nt = 0; nt < 4; nt++)
      s[mt][nt] = __builtin_amdgcn_mfma_f32_16x16x32_bf16(qf[mt], kf[nt],
                    (f32x4){0.f, 0.f, 0.f, 0.f}, 0, 0, 0);
  __builtin_amdgcn_s_setprio(0);

  const int wim = wid & 63;
  const int wy = wim >> 3, wx = wim & 7;
  int labn[4], ch[4], cw[4];
  bool cval[4];
#pragma unroll
  for (int nt = 0; nt < 4; nt++) {
    const int C = (lane & 15) + nt * 16;
    cval[nt] = (C < 49);
    const int cc = cval[nt] ? C : 48;
    ch[nt] = cc / 7; cw[nt] = cc - ch[nt] * 7;
    labn[nt] = reg3(wy * 7 + ch[nt]) * 3 + reg3(wx * 7 + cw[nt]);
  }

#pragma unroll
  for (int mt = 0; mt < 4; mt++) {
    f32x4 rm, sm, inv;
#pragma unroll
    for (int r = 0; r < 4; r++) {
      int R = mt * 16 + ((lane >> 4) << 2) + r; if (R > 48) R = 48;
      const int mh = R / 7, mw = R - (R / 7) * 7;
      const int labm = reg3(wy * 7 + mh) * 3 + reg3(wx * 7 + mw);
#pragma unroll
      for (int nt = 0; nt < 4; nt++) {
        float sv = s[mt][nt][r] * 0.1767766953f
                 + Bl[(mh - ch[nt] + 6) * 13 + (mw - cw[nt] + 6)];
        if (labn[nt] != labm) sv -= 100.f;
        if (!cval[nt]) sv = -3e38f;
        s[mt][nt][r] = sv;
      }
      rm[r] = fmaxf(fmaxf(s[mt][0][r], s[mt][1][r]), fmaxf(s[mt][2][r], s[mt][3][r]));
    }
#pragma unroll
    for (int mk = 1; mk < 16; mk <<= 1)
#pragma unroll
      for (int r = 0; r < 4; r++) rm[r] = fmaxf(rm[r], __shfl_xor(rm[r], mk));
#pragma unroll
    for (int r = 0; r < 4; r++) {
      float acc = 0.f;
#pragma unroll
      for (int nt = 0; nt < 4; nt++) {
        const float p = __expf(s[mt][nt][r] - rm[r]);
        s[mt][nt][r] = p;
        acc += p;
      }
      sm[r] = acc;
    }
#pragma unroll
    for (int mk = 1; mk < 16; mk <<= 1)
#pragma unroll
      for (int r = 0; r < 4; r++) sm[r] += __shfl_xor(sm[r], mk);
#pragma unroll
    for (int r = 0; r < 4; r++) inv[r] = __builtin_amdgcn_rcpf(sm[r]);
#pragma unroll
    for (int nt = 0; nt < 4; nt++)
#pragma unroll
      for (int r = 0; r < 4; r++) {
        const int R = mt * 16 + ((lane >> 4) << 2) + r;
        const int C = (lane & 15) + nt * 16;
        Pl[R * 64 + (C ^ ((R & 7) << 3))] = f2bu(s[mt][nt][r] * inv[r]);
      }
  }

  f32x4 o[4][2];
#pragma unroll
  for (int mt = 0; mt < 4; mt++)
#pragma unroll
    for (int n2 = 0; n2 < 2; n2++) o[mt][n2] = (f32x4){0.f, 0.f, 0.f, 0.f};
  __builtin_amdgcn_s_setprio(1);
#pragma unroll
  for (int kk = 0; kk < 2; kk++) {
    const int kb = kk * 64 + ((lane >> 4) << 4);
    bf16x8 vb[2];
#pragma unroll
    for (int n2 = 0; n2 < 2; n2++) {
      const int d = (lane & 15) + n2 * 16;
      vb[n2] = *(const bf16x8*)((const char*)Vt + d * 128 + (kb ^ ((d & 7) << 4)));
    }
#pragma unroll
    for (int mt = 0; mt < 4; mt++) {
      const int R = (lane & 15) + mt * 16;
      const bf16x8 pa = *(const bf16x8*)((const char*)Pl + R * 128 + (kb ^ ((R & 7) << 4)));
#pragma unroll
      for (int n2 = 0; n2 < 2; n2++)
        o[mt][n2] = __builtin_amdgcn_mfma_f32_16x16x32_bf16(pa, vb[n2], o[mt][n2], 0, 0, 0);
    }
  }
  __builtin_amdgcn_s_setprio(0);

#pragma unroll
  for (int mt = 0; mt < 4; mt++)
#pragma unroll
    for (int r = 0; r < 4; r++) {
      const int R = mt * 16 + ((lane >> 4) << 2) + r;
      if (R < 49) {
        bf16* orow = aout + (size_t)(wid * 49 + R) * 192 + h * 32;
#pragma unroll
        for (int n2 = 0; n2 < 2; n2++)
          orow[n2 * 16 + (lane & 15)] = __float2bfloat16(o[mt][n2][r]);
      }
    }
}

extern "C" void kernel_launch(void* const* d_in, const int* in_sizes, int n_in,
                              void* d_out, int out_size, void* d_ws, size_t ws_size,
                              hipStream_t stream)
{
  (void)in_sizes; (void)n_in; (void)out_size;
  const float* x     = (const float*)d_in[0];
  const float* ln1g  = (const float*)d_in[1];
  const float* ln1b  = (const float*)d_in[2];
  const float* qkvw  = (const float*)d_in[3];
  const float* qkvb  = (const float*)d_in[4];
  const float* projw = (const float*)d_in[5];
  const float* projb = (const float*)d_in[6];
  const float* rpb   = (const float*)d_in[7];
  const float* ln2g  = (const float*)d_in[8];
  const float* ln2b  = (const float*)d_in[9];
  const float* fc1w  = (const float*)d_in[10];
  const float* fc1b  = (const float*)d_in[11];
  const float* fc2w  = (const float*)d_in[12];
  const float* fc2b  = (const float*)d_in[13];
  float* out = (float*)d_out;
  char* ws   = (char*)d_ws;

  // ---- bf16 weight copies at head of ws (884736 B total) ----
  bf16* wqkv = (bf16*)(ws);              // 110592 el
  bf16* wproj = (bf16*)(ws + 221184);    //  36864 el
  bf16* wfc1 = (bf16*)(ws + 294912);     // 147456 el
  bf16* wfc2 = (bf16*)(ws + 589824);     // 147456 el
  cvt_kernel<<<dim3(432), dim3(256), 0, stream>>>(qkvw, wqkv, 110592);
  cvt_kernel<<<dim3(144), dim3(256), 0, stream>>>(projw, wproj, 36864);
  cvt_kernel<<<dim3(576), dim3(256), 0, stream>>>(fc1w, wfc1, 147456);
  cvt_kernel<<<dim3(576), dim3(256), 0, stream>>>(fc2w, wfc2, 147456);

  char* cws = ws + 884736;
  const size_t avail = (ws_size > 884736ull) ? ws_size - 884736ull : 0;

  // ---- attention pipeline, chunked over batch (permutes are batch-local) ----
  int Bc = 32;
  while (Bc > 2 && (size_t)Bc * 4816896ull > avail) Bc >>= 1;
  const int nb = 32 / Bc;
  bf16* qkv_c  = (bf16*)cws;
  bf16* hwin_c = (bf16*)(cws + (size_t)Bc * 3612672ull);   // attnout

  for (int c = 0; c < nb; c++) {
    const int R0 = c * Bc * 3136;
    const int Mc = Bc * 3136;
    const int MT = Mc / 64;
    const int Gq = (MT < 85) ? MT : 85;
    const int Gp = (MT < 256) ? MT : 256;
    plngemm_kernel<0><<<dim3(3, Gq), dim3(512), 0, stream>>>(x, ln1g, ln1b, wqkv, qkvb,
                                                             qkv_c, 576, R0, MT);
    attn_kernel<<<dim3(Bc * 64, 6), dim3(64), 0, stream>>>(qkv_c, rpb, hwin_c);
    pgemm_kernel<<<dim3(1, Gp), dim3(512), 0, stream>>>(hwin_c, wproj, projb, x, out, R0, MT);
  }

  // ---- MLP: fc1 with fused LN2, then fc2 ----
  int Rc = 100352;
  while (Rc > 6272 && (size_t)Rc * 1536ull > avail) Rc >>= 1;
  bf16* a1_c = (bf16*)cws;

  for (int r0 = 0; r0 < 100352; r0 += Rc) {
    const int MT1 = Rc / 64;
    const int G1  = (MT1 < 64) ? MT1 : 64;
    plngemm_kernel<2><<<dim3(4, G1), dim3(512), 0, stream>>>(out + (size_t)r0 * 192,
                                                             ln2g, ln2b, wfc1, fc1b,
                                                             a1_c, 768, 0, MT1);
    gemm_kernel<<<dim3(1, Rc / 128), dim3(512), 0, stream>>>(a1_c, wfc2, fc2b,
                                                             out + (size_t)r0 * 192, 192, 768);
  }
}

// Round 25
// 317.897 us; speedup vs baseline: 1.0944x; 1.0264x over previous
//
#include <hip/hip_runtime.h>
#include <hip/hip_bf16.h>
#include <cstdint>
#include <cstddef>

typedef __hip_bfloat16 bf16;
using f32x4  = __attribute__((ext_vector_type(4))) float;
using bf16x8 = __attribute__((ext_vector_type(8))) short;

#define DEVI __device__ __forceinline__
#define WAITVM(N) asm volatile("s_waitcnt vmcnt(" #N ")" ::: "memory")

DEVI int reg3(int u) { return (u < 49) ? 0 : ((u < 53) ? 1 : 2); }

DEVI unsigned short f2bu(float v) {
  bf16 b = __float2bfloat16(v);
  return *reinterpret_cast<unsigned short*>(&b);
}

// sigmoid-form GELU: v * sigmoid(1.702 v) — 5 VALU ops; error ~1e-3 at these activations.
DEVI float gelu_f(float v) {
  const float e = __expf(-1.702f * v);
  return v * __builtin_amdgcn_rcpf(1.0f + e);
}

DEVI void gload_lds16(const void* g, void* l) {
  __builtin_amdgcn_global_load_lds(
      (const __attribute__((address_space(1))) unsigned int*)g,
      (__attribute__((address_space(3))) unsigned int*)l, 16, 0, 0);
}

// ---------- fp32 -> bf16 weight conversion ----------
__global__ __launch_bounds__(256) void cvt_kernel(const float* __restrict__ src,
                                                  bf16* __restrict__ dst, int n)
{
  const int i = blockIdx.x * 256 + threadIdx.x;
  if (i < n) dst[i] = __float2bfloat16(src[i]);
}

// ---------- persistent-B GEMM + fused LayerNorm A-staging, K=192 ----------
// MODE 0: QKV — A rows = LN1(x[gathered via shift/window +3 map]); bf16 out
// MODE 2: fc1 — A rows = LN2(X linear rows); bf16 out + GELU
// R25: 1D grid with XCD co-location swizzle — the P n-panel blocks of each
// row-group g share bid mod 8 (same XCD L2) so the A-tile is HBM-fetched once.
// Bijective when G%8==0 (fc1: G=64); identity fallback otherwise (QKV: G=85).
template<int MODE>
__global__ __launch_bounds__(512) void plngemm_kernel(const float* __restrict__ X,
                                                      const float* __restrict__ gw,
                                                      const float* __restrict__ bw,
                                                      const bf16* __restrict__ Bt,
                                                      const float* __restrict__ bias,
                                                      bf16* __restrict__ outp,
                                                      int N, int grow0, int MT, int P)
{
  __shared__ short Bp[192 * 192];       // 72 KiB
  __shared__ short La[2][64 * 192];     // 2 x 24 KiB
  const int tid   = threadIdx.x;
  const int lane  = tid & 63;
  const int w     = tid >> 6;
  const int wm    = (w >> 2) * 32;
  const int wn    = (w & 3) * 48;
  const int G     = gridDim.x / P;
  int panel, g;
  {
    const int bid = blockIdx.x;
    if ((G & 7) == 0) {                 // XCD co-location swizzle
      const int r = bid & 7, q = bid >> 3;
      const int qp = q / P;
      g     = r + 8 * qp;
      panel = q - qp * P;
    } else {                            // identity (matches old (x=panel, y=g) order)
      panel = bid % P;
      g     = bid / P;
    }
  }
  const int n0    = panel * 192;
  const int kq    = lane >> 4;
  const int rowid = tid >> 3;           // 0..63
  const int sub   = tid & 7;            // 8 threads per row
  const int c24   = sub * 24;

  float bv[3];
  int ncol[3];
#pragma unroll
  for (int nf = 0; nf < 3; nf++) {
    ncol[nf] = n0 + wn + nf * 16 + (lane & 15);
    bv[nf]   = bias[ncol[nf]];
  }
  float gv[24], bb[24];
#pragma unroll
  for (int i = 0; i < 6; i++) {
    const f32x4 gg = *(const f32x4*)(gw + c24 + 4 * i);
    const f32x4 bz = *(const f32x4*)(bw + c24 + 4 * i);
#pragma unroll
    for (int e = 0; e < 4; e++) { gv[4 * i + e] = gg[e]; bb[4 * i + e] = bz[e]; }
  }

#pragma unroll
  for (int i = 0; i < 9; i++) {
    const int chunk = w * 9 + i;
    const int idx = chunk * 64 + lane;
    const int row = idx / 24;
    const int seg = idx - row * 24;
    const int ksrc = (seg * 8) ^ ((row & 7) << 3);
    gload_lds16(Bt + (size_t)(n0 + row) * 192 + ksrc, Bp + chunk * 512);
  }

  f32x4 vf[6];
  auto issueA = [&](int mt) {
    const float* src;
    if constexpr (MODE == 0) {
      const int gm  = grow0 + mt * 64 + rowid;
      const int wid = gm / 49;
      const int nn  = gm - wid * 49;
      const int b_  = wid >> 6, wim = wid & 63;
      const int wy  = wim >> 3, wx = wim & 7;
      const int ny  = nn / 7, nx = nn - (nn / 7) * 7;
      int i2 = wy * 7 + ny + 3; if (i2 >= 56) i2 -= 56;
      int j2 = wx * 7 + nx + 3; if (j2 >= 56) j2 -= 56;
      src = X + (size_t)(b_ * 3136 + i2 * 56 + j2) * 192 + c24;
    } else {
      src = X + (size_t)(mt * 64 + rowid) * 192 + c24;
    }
#pragma unroll
    for (int i = 0; i < 6; i++) vf[i] = *(const f32x4*)(src + 4 * i);
  };

  auto lnwrite = [&](int buf) {
    float v[24];
#pragma unroll
    for (int i = 0; i < 6; i++)
#pragma unroll
      for (int e = 0; e < 4; e++) v[4 * i + e] = vf[i][e];
    float s = 0.f;
#pragma unroll
    for (int i = 0; i < 24; i++) s += v[i];
    s += __shfl_xor(s, 1); s += __shfl_xor(s, 2); s += __shfl_xor(s, 4);
    const float mu = s * (1.0f / 192.0f);
    float vs = 0.f;
#pragma unroll
    for (int i = 0; i < 24; i++) { const float d = v[i] - mu; vs += d * d; }
    vs += __shfl_xor(vs, 1); vs += __shfl_xor(vs, 2); vs += __shfl_xor(vs, 4);
    const float rstd = rsqrtf(vs * (1.0f / 192.0f) + 1e-5f);
    const float a = rstd, b0 = -mu * rstd;
    const int rx = (rowid & 7) << 4;
#pragma unroll
    for (int c3 = 0; c3 < 3; c3++) {
      bf16x8 pk;
#pragma unroll
      for (int e = 0; e < 8; e++) {
        const int i = c3 * 8 + e;
        pk[e] = (short)f2bu((v[i] * a + b0) * gv[i] + bb[i]);
      }
      *(bf16x8*)((char*)&La[buf][0] + rowid * 384 + ((c24 * 2 + c3 * 16) ^ rx)) = pk;
    }
  };

  if (g < MT) { issueA(g); lnwrite(0); }
  __syncthreads();

  int buf = 0;
  for (int mt = g; mt < MT; mt += G) {
    const bool pf = (mt + G < MT);
    if (pf) issueA(mt + G);
    asm volatile("" ::: "memory");

    const char* LA = (const char*)&La[buf][0];
    f32x4 acc[2][3];
#pragma unroll
    for (int i = 0; i < 2; i++)
#pragma unroll
      for (int j = 0; j < 3; j++) acc[i][j] = (f32x4){0.f, 0.f, 0.f, 0.f};

#pragma unroll
    for (int kk = 0; kk < 6; kk++) {
      const int q = kk * 64 + (kq << 4);
      bf16x8 af[2], bg[3];
#pragma unroll
      for (int mf = 0; mf < 2; mf++) {
        const int ar = wm + mf * 16 + (lane & 15);
        af[mf] = *(const bf16x8*)(LA + ar * 384 + (q ^ ((ar & 7) << 4)));
      }
#pragma unroll
      for (int nf = 0; nf < 3; nf++) {
        const int br = wn + nf * 16 + (lane & 15);
        bg[nf] = *(const bf16x8*)((const char*)Bp + br * 384 + (q ^ ((br & 7) << 4)));
      }
#pragma unroll
      for (int mf = 0; mf < 2; mf++)
#pragma unroll
        for (int nf = 0; nf < 3; nf++)
          acc[mf][nf] = __builtin_amdgcn_mfma_f32_16x16x32_bf16(af[mf], bg[nf], acc[mf][nf], 0, 0, 0);
    }

    const int m0 = mt * 64;
#pragma unroll
    for (int mf = 0; mf < 2; mf++) {
#pragma unroll
      for (int r = 0; r < 4; r++) {
        const int m = m0 + wm + mf * 16 + ((lane >> 4) << 2) + r;
        bf16* O = outp + (size_t)m * N;
#pragma unroll
        for (int nf = 0; nf < 3; nf++) {
          float vvv = acc[mf][nf][r] + bv[nf];
          if constexpr (MODE == 2) vvv = gelu_f(vvv);
          O[ncol[nf]] = __float2bfloat16(vvv);
        }
      }
    }

    if (pf) lnwrite(buf ^ 1);
    asm volatile("s_waitcnt lgkmcnt(0)" ::: "memory");
    __builtin_amdgcn_s_barrier();
    buf ^= 1;
  }
}

// ---------- persistent-B GEMM, K=192 (proj + un-shift scatter + resid) ----------
__global__ __launch_bounds__(512) void pgemm_kernel(const bf16* __restrict__ A,
                                                    const bf16* __restrict__ Bt,
                                                    const float* __restrict__ bias,
                                                    const float* __restrict__ resid,
                                                    float* __restrict__ outv,
                                                    int grow0, int MT)
{
  __shared__ short Bp[192 * 192];
  __shared__ short La[2][64 * 192];
  const int tid  = threadIdx.x;
  const int lane = tid & 63;
  const int w    = tid >> 6;
  const int wm   = (w >> 2) * 32;
  const int wn   = (w & 3) * 48;
  const int n0   = blockIdx.x * 192;
  const int G    = gridDim.y;
  const int g    = blockIdx.y;
  const int kq   = lane >> 4;

  float bv[3];
  int ncol[3];
#pragma unroll
  for (int nf = 0; nf < 3; nf++) {
    ncol[nf] = n0 + wn + nf * 16 + (lane & 15);
    bv[nf]   = bias[ncol[nf]];
  }

#pragma unroll
  for (int i = 0; i < 9; i++) {
    const int chunk = w * 9 + i;
    const int idx = chunk * 64 + lane;
    const int row = idx / 24;
    const int seg = idx - row * 24;
    const int ksrc = (seg * 8) ^ ((row & 7) << 3);
    gload_lds16(Bt + (size_t)(n0 + row) * 192 + ksrc, Bp + chunk * 512);
  }

  auto stageA = [&](int buf, int mt) {
    const int m0 = mt * 64;
#pragma unroll
    for (int i = 0; i < 3; i++) {
      const int chunk = w * 3 + i;
      const int idx = chunk * 64 + lane;
      const int row = idx / 24;
      const int seg = idx - row * 24;
      const int ksrc = (seg * 8) ^ ((row & 7) << 3);
      gload_lds16(A + (size_t)(m0 + row) * 192 + ksrc, &La[buf][0] + chunk * 512);
    }
  };

  int buf = 0;
  if (g < MT) stageA(0, g);
  __syncthreads();

  for (int mt = g; mt < MT; mt += G) {
    WAITVM(48);
    __builtin_amdgcn_s_barrier();

    const char* LA = (const char*)&La[buf][0];
    f32x4 acc[2][3];
#pragma unroll
    for (int i = 0; i < 2; i++)
#pragma unroll
      for (int j = 0; j < 3; j++) acc[i][j] = (f32x4){0.f, 0.f, 0.f, 0.f};

#pragma unroll
    for (int kk = 0; kk < 6; kk++) {
      const int q = kk * 64 + (kq << 4);
      bf16x8 af[2], bg[3];
#pragma unroll
      for (int mf = 0; mf < 2; mf++) {
        const int ar = wm + mf * 16 + (lane & 15);
        af[mf] = *(const bf16x8*)(LA + ar * 384 + (q ^ ((ar & 7) << 4)));
      }
#pragma unroll
      for (int nf = 0; nf < 3; nf++) {
        const int br = wn + nf * 16 + (lane & 15);
        bg[nf] = *(const bf16x8*)((const char*)Bp + br * 384 + (q ^ ((br & 7) << 4)));
      }
#pragma unroll
      for (int mf = 0; mf < 2; mf++)
#pragma unroll
        for (int nf = 0; nf < 3; nf++)
          acc[mf][nf] = __builtin_amdgcn_mfma_f32_16x16x32_bf16(af[mf], bg[nf], acc[mf][nf], 0, 0, 0);
    }

    if (mt + G < MT) stageA(buf ^ 1, mt + G);

    const int m0 = mt * 64;
#pragma unroll
    for (int mf = 0; mf < 2; mf++) {
#pragma unroll
      for (int r = 0; r < 4; r++) {
        const int m = m0 + wm + mf * 16 + ((lane >> 4) << 2) + r;
        const int gm  = grow0 + m;
        const int wid = gm / 49;
        const int nn  = gm - wid * 49;
        const int b_  = wid >> 6, wim = wid & 63;
        const int wy  = wim >> 3, wx = wim & 7;
        const int ny  = nn / 7, nx = nn - (nn / 7) * 7;
        int i = wy * 7 + ny + 3; if (i >= 56) i -= 56;
        int j = wx * 7 + nx + 3; if (j >= 56) j -= 56;
        const size_t t = (size_t)(b_ * 3136 + i * 56 + j) * 192;
#pragma unroll
        for (int nf = 0; nf < 3; nf++)
          outv[t + ncol[nf]] = acc[mf][nf][r] + bv[nf] + resid[t + ncol[nf]];
      }
    }
    buf ^= 1;
  }
}

// ---------- streamed GEMM (fc2: K=768, fp32 +=), counted-vmcnt 2-phase ----------
__global__ __launch_bounds__(512, 4) void gemm_kernel(const bf16* __restrict__ A,
                                                      const bf16* __restrict__ Bt,
                                                      const float* __restrict__ bias,
                                                      void* __restrict__ outv,
                                                      int N, int K)
{
  __shared__ short lds[2][128 * 64 + 192 * 64];
  const int tid  = threadIdx.x;
  const int lane = tid & 63;
  const int w    = tid >> 6;
  const int wm   = (w >> 2) * 64;
  const int wn   = (w & 3) * 48;
  const int m0   = blockIdx.y * 128;
  const int n0   = blockIdx.x * 192;
  const int lrow = lane >> 3;
  const int lseg = lane & 7;
  const int ksw  = (lseg * 8) ^ (lrow << 3);

  f32x4 acc[4][3];
#pragma unroll
  for (int i = 0; i < 4; i++)
#pragma unroll
    for (int j = 0; j < 3; j++) acc[i][j] = (f32x4){0.f, 0.f, 0.f, 0.f};

  const int nk = K >> 6;

  auto issue = [&](int buf, int kt) {
    const int k0 = kt << 6;
    short* LA = &lds[buf][0];
    short* LB = &lds[buf][128 * 64];
#pragma unroll
    for (int i = 0; i < 2; i++) {
      const int chunk = w * 2 + i;
      gload_lds16(A + (size_t)(m0 + chunk * 8 + lrow) * K + (k0 + ksw), LA + chunk * 512);
    }
#pragma unroll
    for (int i = 0; i < 3; i++) {
      const int chunk = w * 3 + i;
      gload_lds16(Bt + (size_t)(n0 + chunk * 8 + lrow) * K + (k0 + ksw), LB + chunk * 512);
    }
  };

  issue(0, 0);
  __syncthreads();
  int buf = 0;

  for (int kt = 0; kt < nk; kt++) {
    if (kt + 1 < nk) {
      issue(buf ^ 1, kt + 1);
      WAITVM(5);
    } else {
      WAITVM(0);
    }
    __builtin_amdgcn_s_barrier();
    const char* LA = (const char*)&lds[buf][0];
    const char* LB = (const char*)&lds[buf][128 * 64];
#pragma unroll
    for (int kk = 0; kk < 2; kk++) {
      bf16x8 af[4], bg[3];
#pragma unroll
      for (int mf = 0; mf < 4; mf++) {
        const int row = wm + mf * 16 + (lane & 15);
        const int kb  = (kk * 64 + ((lane >> 4) << 4)) ^ ((row & 7) << 4);
        af[mf] = *(const bf16x8*)(LA + row * 128 + kb);
      }
#pragma unroll
      for (int nf = 0; nf < 3; nf++) {
        const int row = wn + nf * 16 + (lane & 15);
        const int kb  = (kk * 64 + ((lane >> 4) << 4)) ^ ((row & 7) << 4);
        bg[nf] = *(const bf16x8*)(LB + row * 128 + kb);
      }
#pragma unroll
      for (int mf = 0; mf < 4; mf++)
#pragma unroll
        for (int nf = 0; nf < 3; nf++)
          acc[mf][nf] = __builtin_amdgcn_mfma_f32_16x16x32_bf16(af[mf], bg[nf], acc[mf][nf], 0, 0, 0);
    }
    __builtin_amdgcn_s_barrier();
    buf ^= 1;
  }

  float bv[3];
  int ncol[3];
#pragma unroll
  for (int nf = 0; nf < 3; nf++) {
    ncol[nf] = n0 + wn + nf * 16 + (lane & 15);
    bv[nf]   = bias[ncol[nf]];
  }
#pragma unroll
  for (int mf = 0; mf < 4; mf++) {
#pragma unroll
    for (int r = 0; r < 4; r++) {
      const int m = m0 + wm + mf * 16 + ((lane >> 4) << 2) + r;
      float* O = (float*)outv + (size_t)m * N;
#pragma unroll
      for (int nf = 0; nf < 3; nf++)
        O[ncol[nf]] = acc[mf][nf][r] + bv[nf] + O[ncol[nf]];
    }
  }
}

// ---------- MFMA windowed attention (R7-verified; rcp normalize; T5 setprio) ----------
__global__ __launch_bounds__(64) void attn_kernel(const bf16* __restrict__ qkv,
                                                  const float* __restrict__ rpb,
                                                  bf16* __restrict__ aout)
{
  __shared__ unsigned short Vt[32 * 64];
  __shared__ unsigned short Pl[64 * 64];
  __shared__ float Bl[169];
  const int lane = threadIdx.x;
  const int wid  = blockIdx.x;
  const int h    = blockIdx.y;
  const unsigned short* qkvu = (const unsigned short*)qkv;
  const size_t base = (size_t)wid * 49 * 576 + h * 32;

#pragma unroll
  for (int i = 0; i < 3; i++) {
    const int idx = lane + 64 * i;
    if (idx < 169) Bl[idx] = rpb[idx * 6 + h];
  }
#pragma unroll
  for (int i = 0; i < 8; i++)
    ((unsigned long long*)Vt)[lane + 64 * i] = 0ull;

#pragma unroll
  for (int it = 0; it < 7; it++) {
    const int idx = lane + 64 * it;
    if (idx < 392) {
      const int n  = idx >> 3;
      const int d0 = (idx & 7) * 4;
      ushort4 v = *(const ushort4*)(qkvu + base + (size_t)n * 576 + 384 + d0);
      Vt[(d0 + 0) * 64 + (n ^ (((d0 + 0) & 7) << 3))] = v.x;
      Vt[(d0 + 1) * 64 + (n ^ (((d0 + 1) & 7) << 3))] = v.y;
      Vt[(d0 + 2) * 64 + (n ^ (((d0 + 2) & 7) << 3))] = v.z;
      Vt[(d0 + 3) * 64 + (n ^ (((d0 + 3) & 7) << 3))] = v.w;
    }
  }

  bf16x8 qf[4], kf[4];
#pragma unroll
  for (int t = 0; t < 4; t++) {
    int rq = (lane & 15) + t * 16; if (rq > 48) rq = 48;
    qf[t] = *(const bf16x8*)(qkvu + base + (size_t)rq * 576 + ((lane >> 4) * 8));
    kf[t] = *(const bf16x8*)(qkvu + base + (size_t)rq * 576 + 192 + ((lane >> 4) * 8));
  }

  f32x4 s[4][4];
  __builtin_amdgcn_s_setprio(1);
#pragma unroll
  for (int mt = 0; mt < 4; mt++)
#pragma unroll
    for (int nt = 0; nt < 4; nt++)
      s[mt][nt] = __builtin_amdgcn_mfma_f32_16x16x32_bf16(qf[mt], kf[nt],
                    (f32x4){0.f, 0.f, 0.f, 0.f}, 0, 0, 0);
  __builtin_amdgcn_s_setprio(0);

  const int wim = wid & 63;
  const int wy = wim >> 3, wx = wim & 7;
  int labn[4], ch[4], cw[4];
  bool cval[4];
#pragma unroll
  for (int nt = 0; nt < 4; nt++) {
    const int C = (lane & 15) + nt * 16;
    cval[nt] = (C < 49);
    const int cc = cval[nt] ? C : 48;
    ch[nt] = cc / 7; cw[nt] = cc - ch[nt] * 7;
    labn[nt] = reg3(wy * 7 + ch[nt]) * 3 + reg3(wx * 7 + cw[nt]);
  }

#pragma unroll
  for (int mt = 0; mt < 4; mt++) {
    f32x4 rm, sm, inv;
#pragma unroll
    for (int r = 0; r < 4; r++) {
      int R = mt * 16 + ((lane >> 4) << 2) + r; if (R > 48) R = 48;
      const int mh = R / 7, mw = R - (R / 7) * 7;
      const int labm = reg3(wy * 7 + mh) * 3 + reg3(wx * 7 + mw);
#pragma unroll
      for (int nt = 0; nt < 4; nt++) {
        float sv = s[mt][nt][r] * 0.1767766953f
                 + Bl[(mh - ch[nt] + 6) * 13 + (mw - cw[nt] + 6)];
        if (labn[nt] != labm) sv -= 100.f;
        if (!cval[nt]) sv = -3e38f;
        s[mt][nt][r] = sv;
      }
      rm[r] = fmaxf(fmaxf(s[mt][0][r], s[mt][1][r]), fmaxf(s[mt][2][r], s[mt][3][r]));
    }
#pragma unroll
    for (int mk = 1; mk < 16; mk <<= 1)
#pragma unroll
      for (int r = 0; r < 4; r++) rm[r] = fmaxf(rm[r], __shfl_xor(rm[r], mk));
#pragma unroll
    for (int r = 0; r < 4; r++) {
      float acc = 0.f;
#pragma unroll
      for (int nt = 0; nt < 4; nt++) {
        const float p = __expf(s[mt][nt][r] - rm[r]);
        s[mt][nt][r] = p;
        acc += p;
      }
      sm[r] = acc;
    }
#pragma unroll
    for (int mk = 1; mk < 16; mk <<= 1)
#pragma unroll
      for (int r = 0; r < 4; r++) sm[r] += __shfl_xor(sm[r], mk);
#pragma unroll
    for (int r = 0; r < 4; r++) inv[r] = __builtin_amdgcn_rcpf(sm[r]);
#pragma unroll
    for (int nt = 0; nt < 4; nt++)
#pragma unroll
      for (int r = 0; r < 4; r++) {
        const int R = mt * 16 + ((lane >> 4) << 2) + r;
        const int C = (lane & 15) + nt * 16;
        Pl[R * 64 + (C ^ ((R & 7) << 3))] = f2bu(s[mt][nt][r] * inv[r]);
      }
  }

  f32x4 o[4][2];
#pragma unroll
  for (int mt = 0; mt < 4; mt++)
#pragma unroll
    for (int n2 = 0; n2 < 2; n2++) o[mt][n2] = (f32x4){0.f, 0.f, 0.f, 0.f};
  __builtin_amdgcn_s_setprio(1);
#pragma unroll
  for (int kk = 0; kk < 2; kk++) {
    const int kb = kk * 64 + ((lane >> 4) << 4);
    bf16x8 vb[2];
#pragma unroll
    for (int n2 = 0; n2 < 2; n2++) {
      const int d = (lane & 15) + n2 * 16;
      vb[n2] = *(const bf16x8*)((const char*)Vt + d * 128 + (kb ^ ((d & 7) << 4)));
    }
#pragma unroll
    for (int mt = 0; mt < 4; mt++) {
      const int R = (lane & 15) + mt * 16;
      const bf16x8 pa = *(const bf16x8*)((const char*)Pl + R * 128 + (kb ^ ((R & 7) << 4)));
#pragma unroll
      for (int n2 = 0; n2 < 2; n2++)
        o[mt][n2] = __builtin_amdgcn_mfma_f32_16x16x32_bf16(pa, vb[n2], o[mt][n2], 0, 0, 0);
    }
  }
  __builtin_amdgcn_s_setprio(0);

#pragma unroll
  for (int mt = 0; mt < 4; mt++)
#pragma unroll
    for (int r = 0; r < 4; r++) {
      const int R = mt * 16 + ((lane >> 4) << 2) + r;
      if (R < 49) {
        bf16* orow = aout + (size_t)(wid * 49 + R) * 192 + h * 32;
#pragma unroll
        for (int n2 = 0; n2 < 2; n2++)
          orow[n2 * 16 + (lane & 15)] = __float2bfloat16(o[mt][n2][r]);
      }
    }
}

extern "C" void kernel_launch(void* const* d_in, const int* in_sizes, int n_in,
                              void* d_out, int out_size, void* d_ws, size_t ws_size,
                              hipStream_t stream)
{
  (void)in_sizes; (void)n_in; (void)out_size;
  const float* x     = (const float*)d_in[0];
  const float* ln1g  = (const float*)d_in[1];
  const float* ln1b  = (const float*)d_in[2];
  const float* qkvw  = (const float*)d_in[3];
  const float* qkvb  = (const float*)d_in[4];
  const float* projw = (const float*)d_in[5];
  const float* projb = (const float*)d_in[6];
  const float* rpb   = (const float*)d_in[7];
  const float* ln2g  = (const float*)d_in[8];
  const float* ln2b  = (const float*)d_in[9];
  const float* fc1w  = (const float*)d_in[10];
  const float* fc1b  = (const float*)d_in[11];
  const float* fc2w  = (const float*)d_in[12];
  const float* fc2b  = (const float*)d_in[13];
  float* out = (float*)d_out;
  char* ws   = (char*)d_ws;

  // ---- bf16 weight copies at head of ws (884736 B total) ----
  bf16* wqkv = (bf16*)(ws);              // 110592 el
  bf16* wproj = (bf16*)(ws + 221184);    //  36864 el
  bf16* wfc1 = (bf16*)(ws + 294912);     // 147456 el
  bf16* wfc2 = (bf16*)(ws + 589824);     // 147456 el
  cvt_kernel<<<dim3(432), dim3(256), 0, stream>>>(qkvw, wqkv, 110592);
  cvt_kernel<<<dim3(144), dim3(256), 0, stream>>>(projw, wproj, 36864);
  cvt_kernel<<<dim3(576), dim3(256), 0, stream>>>(fc1w, wfc1, 147456);
  cvt_kernel<<<dim3(576), dim3(256), 0, stream>>>(fc2w, wfc2, 147456);

  char* cws = ws + 884736;
  const size_t avail = (ws_size > 884736ull) ? ws_size - 884736ull : 0;

  // ---- attention pipeline, chunked over batch (permutes are batch-local) ----
  int Bc = 32;
  while (Bc > 2 && (size_t)Bc * 4816896ull > avail) Bc >>= 1;
  const int nb = 32 / Bc;
  bf16* qkv_c  = (bf16*)cws;
  bf16* hwin_c = (bf16*)(cws + (size_t)Bc * 3612672ull);   // attnout

  for (int c = 0; c < nb; c++) {
    const int R0 = c * Bc * 3136;
    const int Mc = Bc * 3136;
    const int MT = Mc / 64;
    const int Gq = (MT < 85) ? MT : 85;
    const int Gp = (MT < 256) ? MT : 256;
    plngemm_kernel<0><<<dim3(3 * Gq), dim3(512), 0, stream>>>(x, ln1g, ln1b, wqkv, qkvb,
                                                              qkv_c, 576, R0, MT, 3);
    attn_kernel<<<dim3(Bc * 64, 6), dim3(64), 0, stream>>>(qkv_c, rpb, hwin_c);
    pgemm_kernel<<<dim3(1, Gp), dim3(512), 0, stream>>>(hwin_c, wproj, projb, x, out, R0, MT);
  }

  // ---- MLP: fc1 with fused LN2 (XCD co-location swizzle), then fc2 ----
  int Rc = 100352;
  while (Rc > 6272 && (size_t)Rc * 1536ull > avail) Rc >>= 1;
  bf16* a1_c = (bf16*)cws;

  for (int r0 = 0; r0 < 100352; r0 += Rc) {
    const int MT1 = Rc / 64;
    const int G1  = (MT1 < 64) ? MT1 : 64;
    plngemm_kernel<2><<<dim3(4 * G1), dim3(512), 0, stream>>>(out + (size_t)r0 * 192,
                                                              ln2g, ln2b, wfc1, fc1b,
                                                              a1_c, 768, 0, MT1, 4);
    gemm_kernel<<<dim3(1, Rc / 128), dim3(512), 0, stream>>>(a1_c, wfc2, fc2b,
                                                             out + (size_t)r0 * 192, 192, 768);
  }
}

// Round 26
// 314.422 us; speedup vs baseline: 1.1065x; 1.0111x over previous
//
#include <hip/hip_runtime.h>
#include <hip/hip_bf16.h>
#include <cstdint>
#include <cstddef>

typedef __hip_bfloat16 bf16;
using f32x4  = __attribute__((ext_vector_type(4))) float;
using bf16x8 = __attribute__((ext_vector_type(8))) short;

#define DEVI __device__ __forceinline__
#define WAITVM(N) asm volatile("s_waitcnt vmcnt(" #N ")" ::: "memory")

DEVI int reg3(int u) { return (u < 49) ? 0 : ((u < 53) ? 1 : 2); }

DEVI unsigned short f2bu(float v) {
  bf16 b = __float2bfloat16(v);
  return *reinterpret_cast<unsigned short*>(&b);
}

// sigmoid-form GELU: v * sigmoid(1.702 v) — 5 VALU ops; error ~1e-3 at these activations.
DEVI float gelu_f(float v) {
  const float e = __expf(-1.702f * v);
  return v * __builtin_amdgcn_rcpf(1.0f + e);
}

DEVI void gload_lds16(const void* g, void* l) {
  __builtin_amdgcn_global_load_lds(
      (const __attribute__((address_space(1))) unsigned int*)g,
      (__attribute__((address_space(3))) unsigned int*)l, 16, 0, 0);
}

// ---------- fp32 -> bf16 weight conversion ----------
__global__ __launch_bounds__(256) void cvt_kernel(const float* __restrict__ src,
                                                  bf16* __restrict__ dst, int n)
{
  const int i = blockIdx.x * 256 + threadIdx.x;
  if (i < n) dst[i] = __float2bfloat16(src[i]);
}

// ---------- persistent-B GEMM + fused LayerNorm A-staging, K=192 ----------
// MODE 0: QKV — A rows = LN1(x[gathered via shift/window +3 map]); bf16 out
// MODE 2: fc1 — A rows = LN2(X linear rows); bf16 out + GELU
// XCD co-location swizzle (measured R25: fc1 FETCH 151->39 MB): the P n-panel
// blocks of each row-group g share bid mod 8 (same XCD L2) so the A-tile is
// HBM-fetched once. Bijective when G%8==0; identity fallback otherwise.
// R26: QKV now launches with G=80 (was 85) to activate the swizzle too.
template<int MODE>
__global__ __launch_bounds__(512) void plngemm_kernel(const float* __restrict__ X,
                                                      const float* __restrict__ gw,
                                                      const float* __restrict__ bw,
                                                      const bf16* __restrict__ Bt,
                                                      const float* __restrict__ bias,
                                                      bf16* __restrict__ outp,
                                                      int N, int grow0, int MT, int P)
{
  __shared__ short Bp[192 * 192];       // 72 KiB
  __shared__ short La[2][64 * 192];     // 2 x 24 KiB
  const int tid   = threadIdx.x;
  const int lane  = tid & 63;
  const int w     = tid >> 6;
  const int wm    = (w >> 2) * 32;
  const int wn    = (w & 3) * 48;
  const int G     = gridDim.x / P;
  int panel, g;
  {
    const int bid = blockIdx.x;
    if ((G & 7) == 0) {                 // XCD co-location swizzle
      const int r = bid & 7, q = bid >> 3;
      const int qp = q / P;
      g     = r + 8 * qp;
      panel = q - qp * P;
    } else {                            // identity
      panel = bid % P;
      g     = bid / P;
    }
  }
  const int n0    = panel * 192;
  const int kq    = lane >> 4;
  const int rowid = tid >> 3;           // 0..63
  const int sub   = tid & 7;            // 8 threads per row
  const int c24   = sub * 24;

  float bv[3];
  int ncol[3];
#pragma unroll
  for (int nf = 0; nf < 3; nf++) {
    ncol[nf] = n0 + wn + nf * 16 + (lane & 15);
    bv[nf]   = bias[ncol[nf]];
  }
  float gv[24], bb[24];
#pragma unroll
  for (int i = 0; i < 6; i++) {
    const f32x4 gg = *(const f32x4*)(gw + c24 + 4 * i);
    const f32x4 bz = *(const f32x4*)(bw + c24 + 4 * i);
#pragma unroll
    for (int e = 0; e < 4; e++) { gv[4 * i + e] = gg[e]; bb[4 * i + e] = bz[e]; }
  }

#pragma unroll
  for (int i = 0; i < 9; i++) {
    const int chunk = w * 9 + i;
    const int idx = chunk * 64 + lane;
    const int row = idx / 24;
    const int seg = idx - row * 24;
    const int ksrc = (seg * 8) ^ ((row & 7) << 3);
    gload_lds16(Bt + (size_t)(n0 + row) * 192 + ksrc, Bp + chunk * 512);
  }

  f32x4 vf[6];
  auto issueA = [&](int mt) {
    const float* src;
    if constexpr (MODE == 0) {
      const int gm  = grow0 + mt * 64 + rowid;
      const int wid = gm / 49;
      const int nn  = gm - wid * 49;
      const int b_  = wid >> 6, wim = wid & 63;
      const int wy  = wim >> 3, wx = wim & 7;
      const int ny  = nn / 7, nx = nn - (nn / 7) * 7;
      int i2 = wy * 7 + ny + 3; if (i2 >= 56) i2 -= 56;
      int j2 = wx * 7 + nx + 3; if (j2 >= 56) j2 -= 56;
      src = X + (size_t)(b_ * 3136 + i2 * 56 + j2) * 192 + c24;
    } else {
      src = X + (size_t)(mt * 64 + rowid) * 192 + c24;
    }
#pragma unroll
    for (int i = 0; i < 6; i++) vf[i] = *(const f32x4*)(src + 4 * i);
  };

  auto lnwrite = [&](int buf) {
    float v[24];
#pragma unroll
    for (int i = 0; i < 6; i++)
#pragma unroll
      for (int e = 0; e < 4; e++) v[4 * i + e] = vf[i][e];
    float s = 0.f;
#pragma unroll
    for (int i = 0; i < 24; i++) s += v[i];
    s += __shfl_xor(s, 1); s += __shfl_xor(s, 2); s += __shfl_xor(s, 4);
    const float mu = s * (1.0f / 192.0f);
    float vs = 0.f;
#pragma unroll
    for (int i = 0; i < 24; i++) { const float d = v[i] - mu; vs += d * d; }
    vs += __shfl_xor(vs, 1); vs += __shfl_xor(vs, 2); vs += __shfl_xor(vs, 4);
    const float rstd = rsqrtf(vs * (1.0f / 192.0f) + 1e-5f);
    const float a = rstd, b0 = -mu * rstd;
    const int rx = (rowid & 7) << 4;
#pragma unroll
    for (int c3 = 0; c3 < 3; c3++) {
      bf16x8 pk;
#pragma unroll
      for (int e = 0; e < 8; e++) {
        const int i = c3 * 8 + e;
        pk[e] = (short)f2bu((v[i] * a + b0) * gv[i] + bb[i]);
      }
      *(bf16x8*)((char*)&La[buf][0] + rowid * 384 + ((c24 * 2 + c3 * 16) ^ rx)) = pk;
    }
  };

  if (g < MT) { issueA(g); lnwrite(0); }
  __syncthreads();

  int buf = 0;
  for (int mt = g; mt < MT; mt += G) {
    const bool pf = (mt + G < MT);
    if (pf) issueA(mt + G);
    asm volatile("" ::: "memory");

    const char* LA = (const char*)&La[buf][0];
    f32x4 acc[2][3];
#pragma unroll
    for (int i = 0; i < 2; i++)
#pragma unroll
      for (int j = 0; j < 3; j++) acc[i][j] = (f32x4){0.f, 0.f, 0.f, 0.f};

#pragma unroll
    for (int kk = 0; kk < 6; kk++) {
      const int q = kk * 64 + (kq << 4);
      bf16x8 af[2], bg[3];
#pragma unroll
      for (int mf = 0; mf < 2; mf++) {
        const int ar = wm + mf * 16 + (lane & 15);
        af[mf] = *(const bf16x8*)(LA + ar * 384 + (q ^ ((ar & 7) << 4)));
      }
#pragma unroll
      for (int nf = 0; nf < 3; nf++) {
        const int br = wn + nf * 16 + (lane & 15);
        bg[nf] = *(const bf16x8*)((const char*)Bp + br * 384 + (q ^ ((br & 7) << 4)));
      }
#pragma unroll
      for (int mf = 0; mf < 2; mf++)
#pragma unroll
        for (int nf = 0; nf < 3; nf++)
          acc[mf][nf] = __builtin_amdgcn_mfma_f32_16x16x32_bf16(af[mf], bg[nf], acc[mf][nf], 0, 0, 0);
    }

    const int m0 = mt * 64;
#pragma unroll
    for (int mf = 0; mf < 2; mf++) {
#pragma unroll
      for (int r = 0; r < 4; r++) {
        const int m = m0 + wm + mf * 16 + ((lane >> 4) << 2) + r;
        bf16* O = outp + (size_t)m * N;
#pragma unroll
        for (int nf = 0; nf < 3; nf++) {
          float vvv = acc[mf][nf][r] + bv[nf];
          if constexpr (MODE == 2) vvv = gelu_f(vvv);
          O[ncol[nf]] = __float2bfloat16(vvv);
        }
      }
    }

    if (pf) lnwrite(buf ^ 1);
    asm volatile("s_waitcnt lgkmcnt(0)" ::: "memory");
    __builtin_amdgcn_s_barrier();
    buf ^= 1;
  }
}

// ---------- persistent-B GEMM, K=192 (proj + un-shift scatter + resid) ----------
__global__ __launch_bounds__(512) void pgemm_kernel(const bf16* __restrict__ A,
                                                    const bf16* __restrict__ Bt,
                                                    const float* __restrict__ bias,
                                                    const float* __restrict__ resid,
                                                    float* __restrict__ outv,
                                                    int grow0, int MT)
{
  __shared__ short Bp[192 * 192];
  __shared__ short La[2][64 * 192];
  const int tid  = threadIdx.x;
  const int lane = tid & 63;
  const int w    = tid >> 6;
  const int wm   = (w >> 2) * 32;
  const int wn   = (w & 3) * 48;
  const int n0   = blockIdx.x * 192;
  const int G    = gridDim.y;
  const int g    = blockIdx.y;
  const int kq   = lane >> 4;

  float bv[3];
  int ncol[3];
#pragma unroll
  for (int nf = 0; nf < 3; nf++) {
    ncol[nf] = n0 + wn + nf * 16 + (lane & 15);
    bv[nf]   = bias[ncol[nf]];
  }

#pragma unroll
  for (int i = 0; i < 9; i++) {
    const int chunk = w * 9 + i;
    const int idx = chunk * 64 + lane;
    const int row = idx / 24;
    const int seg = idx - row * 24;
    const int ksrc = (seg * 8) ^ ((row & 7) << 3);
    gload_lds16(Bt + (size_t)(n0 + row) * 192 + ksrc, Bp + chunk * 512);
  }

  auto stageA = [&](int buf, int mt) {
    const int m0 = mt * 64;
#pragma unroll
    for (int i = 0; i < 3; i++) {
      const int chunk = w * 3 + i;
      const int idx = chunk * 64 + lane;
      const int row = idx / 24;
      const int seg = idx - row * 24;
      const int ksrc = (seg * 8) ^ ((row & 7) << 3);
      gload_lds16(A + (size_t)(m0 + row) * 192 + ksrc, &La[buf][0] + chunk * 512);
    }
  };

  int buf = 0;
  if (g < MT) stageA(0, g);
  __syncthreads();

  for (int mt = g; mt < MT; mt += G) {
    WAITVM(48);
    __builtin_amdgcn_s_barrier();

    const char* LA = (const char*)&La[buf][0];
    f32x4 acc[2][3];
#pragma unroll
    for (int i = 0; i < 2; i++)
#pragma unroll
      for (int j = 0; j < 3; j++) acc[i][j] = (f32x4){0.f, 0.f, 0.f, 0.f};

#pragma unroll
    for (int kk = 0; kk < 6; kk++) {
      const int q = kk * 64 + (kq << 4);
      bf16x8 af[2], bg[3];
#pragma unroll
      for (int mf = 0; mf < 2; mf++) {
        const int ar = wm + mf * 16 + (lane & 15);
        af[mf] = *(const bf16x8*)(LA + ar * 384 + (q ^ ((ar & 7) << 4)));
      }
#pragma unroll
      for (int nf = 0; nf < 3; nf++) {
        const int br = wn + nf * 16 + (lane & 15);
        bg[nf] = *(const bf16x8*)((const char*)Bp + br * 384 + (q ^ ((br & 7) << 4)));
      }
#pragma unroll
      for (int mf = 0; mf < 2; mf++)
#pragma unroll
        for (int nf = 0; nf < 3; nf++)
          acc[mf][nf] = __builtin_amdgcn_mfma_f32_16x16x32_bf16(af[mf], bg[nf], acc[mf][nf], 0, 0, 0);
    }

    if (mt + G < MT) stageA(buf ^ 1, mt + G);

    const int m0 = mt * 64;
#pragma unroll
    for (int mf = 0; mf < 2; mf++) {
#pragma unroll
      for (int r = 0; r < 4; r++) {
        const int m = m0 + wm + mf * 16 + ((lane >> 4) << 2) + r;
        const int gm  = grow0 + m;
        const int wid = gm / 49;
        const int nn  = gm - wid * 49;
        const int b_  = wid >> 6, wim = wid & 63;
        const int wy  = wim >> 3, wx = wim & 7;
        const int ny  = nn / 7, nx = nn - (nn / 7) * 7;
        int i = wy * 7 + ny + 3; if (i >= 56) i -= 56;
        int j = wx * 7 + nx + 3; if (j >= 56) j -= 56;
        const size_t t = (size_t)(b_ * 3136 + i * 56 + j) * 192;
#pragma unroll
        for (int nf = 0; nf < 3; nf++)
          outv[t + ncol[nf]] = acc[mf][nf][r] + bv[nf] + resid[t + ncol[nf]];
      }
    }
    buf ^= 1;
  }
}

// ---------- streamed GEMM (fc2: K=768, fp32 +=), counted-vmcnt 2-phase ----------
__global__ __launch_bounds__(512, 4) void gemm_kernel(const bf16* __restrict__ A,
                                                      const bf16* __restrict__ Bt,
                                                      const float* __restrict__ bias,
                                                      void* __restrict__ outv,
                                                      int N, int K)
{
  __shared__ short lds[2][128 * 64 + 192 * 64];
  const int tid  = threadIdx.x;
  const int lane = tid & 63;
  const int w    = tid >> 6;
  const int wm   = (w >> 2) * 64;
  const int wn   = (w & 3) * 48;
  const int m0   = blockIdx.y * 128;
  const int n0   = blockIdx.x * 192;
  const int lrow = lane >> 3;
  const int lseg = lane & 7;
  const int ksw  = (lseg * 8) ^ (lrow << 3);

  f32x4 acc[4][3];
#pragma unroll
  for (int i = 0; i < 4; i++)
#pragma unroll
    for (int j = 0; j < 3; j++) acc[i][j] = (f32x4){0.f, 0.f, 0.f, 0.f};

  const int nk = K >> 6;

  auto issue = [&](int buf, int kt) {
    const int k0 = kt << 6;
    short* LA = &lds[buf][0];
    short* LB = &lds[buf][128 * 64];
#pragma unroll
    for (int i = 0; i < 2; i++) {
      const int chunk = w * 2 + i;
      gload_lds16(A + (size_t)(m0 + chunk * 8 + lrow) * K + (k0 + ksw), LA + chunk * 512);
    }
#pragma unroll
    for (int i = 0; i < 3; i++) {
      const int chunk = w * 3 + i;
      gload_lds16(Bt + (size_t)(n0 + chunk * 8 + lrow) * K + (k0 + ksw), LB + chunk * 512);
    }
  };

  issue(0, 0);
  __syncthreads();
  int buf = 0;

  for (int kt = 0; kt < nk; kt++) {
    if (kt + 1 < nk) {
      issue(buf ^ 1, kt + 1);
      WAITVM(5);
    } else {
      WAITVM(0);
    }
    __builtin_amdgcn_s_barrier();
    const char* LA = (const char*)&lds[buf][0];
    const char* LB = (const char*)&lds[buf][128 * 64];
#pragma unroll
    for (int kk = 0; kk < 2; kk++) {
      bf16x8 af[4], bg[3];
#pragma unroll
      for (int mf = 0; mf < 4; mf++) {
        const int row = wm + mf * 16 + (lane & 15);
        const int kb  = (kk * 64 + ((lane >> 4) << 4)) ^ ((row & 7) << 4);
        af[mf] = *(const bf16x8*)(LA + row * 128 + kb);
      }
#pragma unroll
      for (int nf = 0; nf < 3; nf++) {
        const int row = wn + nf * 16 + (lane & 15);
        const int kb  = (kk * 64 + ((lane >> 4) << 4)) ^ ((row & 7) << 4);
        bg[nf] = *(const bf16x8*)(LB + row * 128 + kb);
      }
#pragma unroll
      for (int mf = 0; mf < 4; mf++)
#pragma unroll
        for (int nf = 0; nf < 3; nf++)
          acc[mf][nf] = __builtin_amdgcn_mfma_f32_16x16x32_bf16(af[mf], bg[nf], acc[mf][nf], 0, 0, 0);
    }
    __builtin_amdgcn_s_barrier();
    buf ^= 1;
  }

  float bv[3];
  int ncol[3];
#pragma unroll
  for (int nf = 0; nf < 3; nf++) {
    ncol[nf] = n0 + wn + nf * 16 + (lane & 15);
    bv[nf]   = bias[ncol[nf]];
  }
#pragma unroll
  for (int mf = 0; mf < 4; mf++) {
#pragma unroll
    for (int r = 0; r < 4; r++) {
      const int m = m0 + wm + mf * 16 + ((lane >> 4) << 2) + r;
      float* O = (float*)outv + (size_t)m * N;
#pragma unroll
      for (int nf = 0; nf < 3; nf++)
        O[ncol[nf]] = acc[mf][nf][r] + bv[nf] + O[ncol[nf]];
    }
  }
}

// ---------- MFMA windowed attention (R7-verified; rcp normalize; T5 setprio) ----------
__global__ __launch_bounds__(64) void attn_kernel(const bf16* __restrict__ qkv,
                                                  const float* __restrict__ rpb,
                                                  bf16* __restrict__ aout)
{
  __shared__ unsigned short Vt[32 * 64];
  __shared__ unsigned short Pl[64 * 64];
  __shared__ float Bl[169];
  const int lane = threadIdx.x;
  const int wid  = blockIdx.x;
  const int h    = blockIdx.y;
  const unsigned short* qkvu = (const unsigned short*)qkv;
  const size_t base = (size_t)wid * 49 * 576 + h * 32;

#pragma unroll
  for (int i = 0; i < 3; i++) {
    const int idx = lane + 64 * i;
    if (idx < 169) Bl[idx] = rpb[idx * 6 + h];
  }
#pragma unroll
  for (int i = 0; i < 8; i++)
    ((unsigned long long*)Vt)[lane + 64 * i] = 0ull;

#pragma unroll
  for (int it = 0; it < 7; it++) {
    const int idx = lane + 64 * it;
    if (idx < 392) {
      const int n  = idx >> 3;
      const int d0 = (idx & 7) * 4;
      ushort4 v = *(const ushort4*)(qkvu + base + (size_t)n * 576 + 384 + d0);
      Vt[(d0 + 0) * 64 + (n ^ (((d0 + 0) & 7) << 3))] = v.x;
      Vt[(d0 + 1) * 64 + (n ^ (((d0 + 1) & 7) << 3))] = v.y;
      Vt[(d0 + 2) * 64 + (n ^ (((d0 + 2) & 7) << 3))] = v.z;
      Vt[(d0 + 3) * 64 + (n ^ (((d0 + 3) & 7) << 3))] = v.w;
    }
  }

  bf16x8 qf[4], kf[4];
#pragma unroll
  for (int t = 0; t < 4; t++) {
    int rq = (lane & 15) + t * 16; if (rq > 48) rq = 48;
    qf[t] = *(const bf16x8*)(qkvu + base + (size_t)rq * 576 + ((lane >> 4) * 8));
    kf[t] = *(const bf16x8*)(qkvu + base + (size_t)rq * 576 + 192 + ((lane >> 4) * 8));
  }

  f32x4 s[4][4];
  __builtin_amdgcn_s_setprio(1);
#pragma unroll
  for (int mt = 0; mt < 4; mt++)
#pragma unroll
    for (int nt = 0; nt < 4; nt++)
      s[mt][nt] = __builtin_amdgcn_mfma_f32_16x16x32_bf16(qf[mt], kf[nt],
                    (f32x4){0.f, 0.f, 0.f, 0.f}, 0, 0, 0);
  __builtin_amdgcn_s_setprio(0);

  const int wim = wid & 63;
  const int wy = wim >> 3, wx = wim & 7;
  int labn[4], ch[4], cw[4];
  bool cval[4];
#pragma unroll
  for (int nt = 0; nt < 4; nt++) {
    const int C = (lane & 15) + nt * 16;
    cval[nt] = (C < 49);
    const int cc = cval[nt] ? C : 48;
    ch[nt] = cc / 7; cw[nt] = cc - ch[nt] * 7;
    labn[nt] = reg3(wy * 7 + ch[nt]) * 3 + reg3(wx * 7 + cw[nt]);
  }

#pragma unroll
  for (int mt = 0; mt < 4; mt++) {
    f32x4 rm, sm, inv;
#pragma unroll
    for (int r = 0; r < 4; r++) {
      int R = mt * 16 + ((lane >> 4) << 2) + r; if (R > 48) R = 48;
      const int mh = R / 7, mw = R - (R / 7) * 7;
      const int labm = reg3(wy * 7 + mh) * 3 + reg3(wx * 7 + mw);
#pragma unroll
      for (int nt = 0; nt < 4; nt++) {
        float sv = s[mt][nt][r] * 0.1767766953f
                 + Bl[(mh - ch[nt] + 6) * 13 + (mw - cw[nt] + 6)];
        if (labn[nt] != labm) sv -= 100.f;
        if (!cval[nt]) sv = -3e38f;
        s[mt][nt][r] = sv;
      }
      rm[r] = fmaxf(fmaxf(s[mt][0][r], s[mt][1][r]), fmaxf(s[mt][2][r], s[mt][3][r]));
    }
#pragma unroll
    for (int mk = 1; mk < 16; mk <<= 1)
#pragma unroll
      for (int r = 0; r < 4; r++) rm[r] = fmaxf(rm[r], __shfl_xor(rm[r], mk));
#pragma unroll
    for (int r = 0; r < 4; r++) {
      float acc = 0.f;
#pragma unroll
      for (int nt = 0; nt < 4; nt++) {
        const float p = __expf(s[mt][nt][r] - rm[r]);
        s[mt][nt][r] = p;
        acc += p;
      }
      sm[r] = acc;
    }
#pragma unroll
    for (int mk = 1; mk < 16; mk <<= 1)
#pragma unroll
      for (int r = 0; r < 4; r++) sm[r] += __shfl_xor(sm[r], mk);
#pragma unroll
    for (int r = 0; r < 4; r++) inv[r] = __builtin_amdgcn_rcpf(sm[r]);
#pragma unroll
    for (int nt = 0; nt < 4; nt++)
#pragma unroll
      for (int r = 0; r < 4; r++) {
        const int R = mt * 16 + ((lane >> 4) << 2) + r;
        const int C = (lane & 15) + nt * 16;
        Pl[R * 64 + (C ^ ((R & 7) << 3))] = f2bu(s[mt][nt][r] * inv[r]);
      }
  }

  f32x4 o[4][2];
#pragma unroll
  for (int mt = 0; mt < 4; mt++)
#pragma unroll
    for (int n2 = 0; n2 < 2; n2++) o[mt][n2] = (f32x4){0.f, 0.f, 0.f, 0.f};
  __builtin_amdgcn_s_setprio(1);
#pragma unroll
  for (int kk = 0; kk < 2; kk++) {
    const int kb = kk * 64 + ((lane >> 4) << 4);
    bf16x8 vb[2];
#pragma unroll
    for (int n2 = 0; n2 < 2; n2++) {
      const int d = (lane & 15) + n2 * 16;
      vb[n2] = *(const bf16x8*)((const char*)Vt + d * 128 + (kb ^ ((d & 7) << 4)));
    }
#pragma unroll
    for (int mt = 0; mt < 4; mt++) {
      const int R = (lane & 15) + mt * 16;
      const bf16x8 pa = *(const bf16x8*)((const char*)Pl + R * 128 + (kb ^ ((R & 7) << 4)));
#pragma unroll
      for (int n2 = 0; n2 < 2; n2++)
        o[mt][n2] = __builtin_amdgcn_mfma_f32_16x16x32_bf16(pa, vb[n2], o[mt][n2], 0, 0, 0);
    }
  }
  __builtin_amdgcn_s_setprio(0);

#pragma unroll
  for (int mt = 0; mt < 4; mt++)
#pragma unroll
    for (int r = 0; r < 4; r++) {
      const int R = mt * 16 + ((lane >> 4) << 2) + r;
      if (R < 49) {
        bf16* orow = aout + (size_t)(wid * 49 + R) * 192 + h * 32;
#pragma unroll
        for (int n2 = 0; n2 < 2; n2++)
          orow[n2 * 16 + (lane & 15)] = __float2bfloat16(o[mt][n2][r]);
      }
    }
}

extern "C" void kernel_launch(void* const* d_in, const int* in_sizes, int n_in,
                              void* d_out, int out_size, void* d_ws, size_t ws_size,
                              hipStream_t stream)
{
  (void)in_sizes; (void)n_in; (void)out_size;
  const float* x     = (const float*)d_in[0];
  const float* ln1g  = (const float*)d_in[1];
  const float* ln1b  = (const float*)d_in[2];
  const float* qkvw  = (const float*)d_in[3];
  const float* qkvb  = (const float*)d_in[4];
  const float* projw = (const float*)d_in[5];
  const float* projb = (const float*)d_in[6];
  const float* rpb   = (const float*)d_in[7];
  const float* ln2g  = (const float*)d_in[8];
  const float* ln2b  = (const float*)d_in[9];
  const float* fc1w  = (const float*)d_in[10];
  const float* fc1b  = (const float*)d_in[11];
  const float* fc2w  = (const float*)d_in[12];
  const float* fc2b  = (const float*)d_in[13];
  float* out = (float*)d_out;
  char* ws   = (char*)d_ws;

  // ---- bf16 weight copies at head of ws (884736 B total) ----
  bf16* wqkv = (bf16*)(ws);              // 110592 el
  bf16* wproj = (bf16*)(ws + 221184);    //  36864 el
  bf16* wfc1 = (bf16*)(ws + 294912);     // 147456 el
  bf16* wfc2 = (bf16*)(ws + 589824);     // 147456 el
  cvt_kernel<<<dim3(432), dim3(256), 0, stream>>>(qkvw, wqkv, 110592);
  cvt_kernel<<<dim3(144), dim3(256), 0, stream>>>(projw, wproj, 36864);
  cvt_kernel<<<dim3(576), dim3(256), 0, stream>>>(fc1w, wfc1, 147456);
  cvt_kernel<<<dim3(576), dim3(256), 0, stream>>>(fc2w, wfc2, 147456);

  char* cws = ws + 884736;
  const size_t avail = (ws_size > 884736ull) ? ws_size - 884736ull : 0;

  // ---- attention pipeline, chunked over batch (permutes are batch-local) ----
  int Bc = 32;
  while (Bc > 2 && (size_t)Bc * 4816896ull > avail) Bc >>= 1;
  const int nb = 32 / Bc;
  bf16* qkv_c  = (bf16*)cws;
  bf16* hwin_c = (bf16*)(cws + (size_t)Bc * 3612672ull);   // attnout

  for (int c = 0; c < nb; c++) {
    const int R0 = c * Bc * 3136;
    const int Mc = Bc * 3136;
    const int MT = Mc / 64;
    // Gq multiple of 8 to activate XCD co-location (R26: 80, was 85)
    int Gq = (MT < 80) ? MT : 80;
    const int Gp = (MT < 256) ? MT : 256;
    plngemm_kernel<0><<<dim3(3 * Gq), dim3(512), 0, stream>>>(x, ln1g, ln1b, wqkv, qkvb,
                                                              qkv_c, 576, R0, MT, 3);
    attn_kernel<<<dim3(Bc * 64, 6), dim3(64), 0, stream>>>(qkv_c, rpb, hwin_c);
    pgemm_kernel<<<dim3(1, Gp), dim3(512), 0, stream>>>(hwin_c, wproj, projb, x, out, R0, MT);
  }

  // ---- MLP: fc1 with fused LN2 (XCD co-location swizzle), then fc2 ----
  int Rc = 100352;
  while (Rc > 6272 && (size_t)Rc * 1536ull > avail) Rc >>= 1;
  bf16* a1_c = (bf16*)cws;

  for (int r0 = 0; r0 < 100352; r0 += Rc) {
    const int MT1 = Rc / 64;
    const int G1  = (MT1 < 64) ? MT1 : 64;
    plngemm_kernel<2><<<dim3(4 * G1), dim3(512), 0, stream>>>(out + (size_t)r0 * 192,
                                                              ln2g, ln2b, wfc1, fc1b,
                                                              a1_c, 768, 0, MT1, 4);
    gemm_kernel<<<dim3(1, Rc / 128), dim3(512), 0, stream>>>(a1_c, wfc2, fc2b,
                                                             out + (size_t)r0 * 192, 192, 768);
  }
}